// Round 1
// baseline (2063.789 us; speedup 1.0000x reference)
//
#include <hip/hip_runtime.h>
#include <hip/hip_bf16.h>
#include <math.h>

#define S 2048
#define D 1024
#define NH 16
#define NKV 4
#define HD 64
#define QKV_N 1536          // (NH + 2*NKV) * HD
#define NE 8
#define NI 1024
#define EPS 1e-6f

// ---------------------------------------------------------------- rmsnorm(D)
__global__ void rmsnorm_kernel(const float* __restrict__ in, const float* __restrict__ w,
                               float* __restrict__ out) {
  int t = blockIdx.x;
  int tid = threadIdx.x;
  const float* row = in + (size_t)t * D;
  float v[4];
  float ss = 0.f;
#pragma unroll
  for (int i = 0; i < 4; ++i) {
    v[i] = row[tid + i * 256];
    ss += v[i] * v[i];
  }
#pragma unroll
  for (int off = 32; off; off >>= 1) ss += __shfl_xor(ss, off);
  __shared__ float wsum[4];
  int wave = tid >> 6;
  if ((tid & 63) == 0) wsum[wave] = ss;
  __syncthreads();
  float tot = wsum[0] + wsum[1] + wsum[2] + wsum[3];
  float r = rsqrtf(tot / (float)D + EPS);
  float* orow = out + (size_t)t * D;
#pragma unroll
  for (int i = 0; i < 4; ++i) {
    int d = tid + i * 256;
    orow[d] = v[i] * r * w[d];
  }
}

// ---------------------------------------------------------------- plain GEMM
// C[M,N] = A[M,K] @ B[K,N] (+ Cadd). M%64==0, N%64==0, K%16==0.
__global__ void gemm_kernel(const float* __restrict__ A, const float* __restrict__ B,
                            const float* __restrict__ Cadd, float* __restrict__ C,
                            int M, int N, int K) {
  __shared__ float As[16][68];   // stride 68 floats = 272B (16B-aligned rows)
  __shared__ float Bs[16][64];
  int bm = blockIdx.y * 64, bn = blockIdx.x * 64;
  int tid = threadIdx.x;
  int tr = tid >> 4, tc = tid & 15;
  float acc[4][4] = {};
  for (int k0 = 0; k0 < K; k0 += 16) {
#pragma unroll
    for (int i = 0; i < 4; ++i) {
      int idx = tid + i * 256;
      int rr = idx >> 4, cc = idx & 15;
      As[cc][rr] = A[(size_t)(bm + rr) * K + k0 + cc];
      int rb = idx >> 6, cb = idx & 63;
      Bs[rb][cb] = B[(size_t)(k0 + rb) * N + bn + cb];
    }
    __syncthreads();
#pragma unroll
    for (int kk = 0; kk < 16; ++kk) {
      float a[4], b[4];
#pragma unroll
      for (int i = 0; i < 4; ++i) a[i] = As[kk][tr * 4 + i];
#pragma unroll
      for (int j = 0; j < 4; ++j) b[j] = Bs[kk][tc * 4 + j];
#pragma unroll
      for (int i = 0; i < 4; ++i)
#pragma unroll
        for (int j = 0; j < 4; ++j) acc[i][j] += a[i] * b[j];
    }
    __syncthreads();
  }
#pragma unroll
  for (int i = 0; i < 4; ++i) {
    int r = bm + tr * 4 + i;
#pragma unroll
    for (int j = 0; j < 4; ++j) {
      size_t idx = (size_t)r * N + bn + tc * 4 + j;
      C[idx] = acc[i][j] + (Cadd ? Cadd[idx] : 0.f);
    }
  }
}

// --------------------------------------------- q/k head rmsnorm + RoPE
__global__ void qkv_post_kernel(const float* __restrict__ qkv,
                                const float* __restrict__ qw, const float* __restrict__ kw,
                                const float* __restrict__ cosb, const float* __restrict__ sinb,
                                float* __restrict__ qout, float* __restrict__ kout) {
  int t = blockIdx.x;
  int u = blockIdx.y * 4 + (threadIdx.x >> 6);   // 0..19: 16 q heads then 4 k heads
  int lane = threadIdx.x & 63;
  bool isq = (u < NH);
  int h = isq ? u : (u - NH);
  size_t src = (size_t)t * QKV_N + (isq ? (h * HD) : (NH * HD + h * HD)) + lane;
  float xv = qkv[src];
  float ss = xv * xv;
#pragma unroll
  for (int off = 32; off; off >>= 1) ss += __shfl_xor(ss, off);
  float r = rsqrtf(ss * (1.f / 64.f) + EPS);
  float xn = xv * r * (isq ? qw[lane] : kw[lane]);
  float other = __shfl_xor(xn, 32);
  float rot = (lane < 32) ? -other : other;
  float res = xn * cosb[t * 64 + lane] + rot * sinb[t * 64 + lane];
  if (isq) qout[(size_t)t * (NH * HD) + h * HD + lane] = res;
  else     kout[(size_t)t * (NKV * HD) + h * HD + lane] = res;
}

// --------------------------------------------- block-causal flash attention
// grid (S/32, NH), block 256. q-tile = 32 rows = exactly one mask block -> no masking.
__global__ void attn_kernel(const float* __restrict__ q, const float* __restrict__ k,
                            const float* __restrict__ qkv, float* __restrict__ attn) {
  int qb = blockIdx.x, h = blockIdx.y;
  int kvh = h >> 2;                       // rep = 4
  __shared__ float Qs[32][65], Ks[32][65], Vs[32][65], Ss[32][33];
  __shared__ float mrow[32], lrow[32], arow[32];
  int tid = threadIdx.x;
  for (int i = tid; i < 32 * 64; i += 256) {
    int r = i >> 6, c = i & 63;
    Qs[r][c] = q[(size_t)(qb * 32 + r) * (NH * HD) + h * HD + c] * 0.125f;
  }
  if (tid < 32) { mrow[tid] = -1e30f; lrow[tid] = 0.f; }
  int r = tid >> 3;
  int cg = (tid & 7) * 8;
  float o[8] = {0, 0, 0, 0, 0, 0, 0, 0};
  __syncthreads();
  for (int kb = 0; kb <= qb; ++kb) {
    for (int i = tid; i < 32 * 64; i += 256) {
      int rr = i >> 6, c = i & 63;
      Ks[rr][c] = k[(size_t)(kb * 32 + rr) * (NKV * HD) + kvh * HD + c];
      Vs[rr][c] = qkv[(size_t)(kb * 32 + rr) * QKV_N + (NH + NKV) * HD + kvh * HD + c];
    }
    __syncthreads();
    {
      int sr = tid >> 3, sc0 = (tid & 7) * 4;
#pragma unroll
      for (int j = 0; j < 4; ++j) {
        float acc = 0.f;
        for (int dd = 0; dd < 64; ++dd) acc += Qs[sr][dd] * Ks[sc0 + j][dd];
        Ss[sr][sc0 + j] = acc;
      }
    }
    __syncthreads();
    if (tid < 32) {
      float mold = mrow[tid];
      float mx = mold;
      for (int j = 0; j < 32; ++j) mx = fmaxf(mx, Ss[tid][j]);
      float alpha = __expf(mold - mx);
      float sum = 0.f;
      for (int j = 0; j < 32; ++j) {
        float pv = __expf(Ss[tid][j] - mx);
        Ss[tid][j] = pv;
        sum += pv;
      }
      lrow[tid] = lrow[tid] * alpha + sum;
      mrow[tid] = mx;
      arow[tid] = alpha;
    }
    __syncthreads();
    float al = arow[r];
#pragma unroll
    for (int c = 0; c < 8; ++c) {
      float acc = 0.f;
      for (int j = 0; j < 32; ++j) acc += Ss[r][j] * Vs[j][cg + c];
      o[c] = o[c] * al + acc;
    }
    __syncthreads();
  }
  float inv = 1.f / lrow[r];
#pragma unroll
  for (int c = 0; c < 8; ++c)
    attn[(size_t)(qb * 32 + r) * (NH * HD) + h * HD + cg + c] = o[c] * inv;
}

// ---------------------------------------------------------------- router
__global__ void zero_counts_kernel(int* counts) {
  if (threadIdx.x < NE) counts[threadIdx.x] = 0;
}

__global__ void router_kernel(const float* __restrict__ h2, const float* __restrict__ rw,
                              int* counts, int* tok_list, int* topk_e, int* topk_pos,
                              float* topk_w) {
  int t = blockIdx.x;
  int lane = threadIdx.x;   // 64
  float p[NE] = {};
  for (int d = lane; d < D; d += 64) {
    float hv = h2[(size_t)t * D + d];
#pragma unroll
    for (int e = 0; e < NE; ++e) p[e] += hv * rw[d * NE + e];
  }
#pragma unroll
  for (int off = 32; off; off >>= 1)
#pragma unroll
    for (int e = 0; e < NE; ++e) p[e] += __shfl_xor(p[e], off);
  if (lane == 0) {
    float mx = p[0];
#pragma unroll
    for (int e = 1; e < NE; ++e) mx = fmaxf(mx, p[e]);
    float ex[NE];
#pragma unroll
    for (int e = 0; e < NE; ++e) ex[e] = __expf(p[e] - mx);
    int e0 = 0;
#pragma unroll
    for (int e = 1; e < NE; ++e) if (ex[e] > ex[e0]) e0 = e;
    int e1 = (e0 == 0) ? 1 : 0;
#pragma unroll
    for (int e = 0; e < NE; ++e) if (e != e0 && ex[e] > ex[e1]) e1 = e;
    float w0 = ex[e0] / (ex[e0] + ex[e1]);
    float w1 = ex[e1] / (ex[e0] + ex[e1]);
    int pos0 = atomicAdd(&counts[e0], 1);
    int pos1 = atomicAdd(&counts[e1], 1);
    tok_list[e0 * S + pos0] = t;
    tok_list[e1 * S + pos1] = t;
    topk_e[2 * t] = e0;  topk_e[2 * t + 1] = e1;
    topk_pos[2 * t] = pos0;  topk_pos[2 * t + 1] = pos1;
    topk_w[2 * t] = w0;  topk_w[2 * t + 1] = w1;
  }
}

__global__ void scan_kernel(const int* counts, int* offsets) {
  if (threadIdx.x == 0) {
    int acc = 0;
    for (int e = 0; e < NE; ++e) { offsets[e] = acc; acc += counts[e]; }
  }
}

// ------------------------------------- fused gate/up GEMM (optionally gathered)
// Cact[obase+pos, :] = silu(A[row]@Wg_e) * (A[row]@Wu_e)
__global__ void gu_kernel(const float* __restrict__ A,
                          const float* __restrict__ Wg, const float* __restrict__ Wu,
                          float* __restrict__ Cact,
                          const int* __restrict__ tok_list, const int* __restrict__ counts,
                          const int* __restrict__ offsets) {
  int e = blockIdx.z;
  int cnt = counts ? counts[e] : S;
  int bm = blockIdx.y * 64;
  if (bm >= cnt) return;
  int bn = blockIdx.x * 64;
  const float* Bg = Wg + (size_t)e * D * NI;
  const float* Bu = Wu + (size_t)e * D * NI;
  int obase = offsets ? offsets[e] : 0;
  __shared__ float As[16][68];
  __shared__ float Bgs[16][64];
  __shared__ float Bus[16][64];
  __shared__ int rowidx[64];
  int tid = threadIdx.x;
  if (tid < 64) {
    int pos = bm + tid;
    rowidx[tid] = (pos < cnt) ? (tok_list ? tok_list[e * S + pos] : pos) : 0;
  }
  __syncthreads();
  int tr = tid >> 4, tc = tid & 15;
  float accg[4][4] = {}, accu[4][4] = {};
  for (int k0 = 0; k0 < D; k0 += 16) {
#pragma unroll
    for (int i = 0; i < 4; ++i) {
      int idx = tid + i * 256;
      int rr = idx >> 4, cc = idx & 15;
      As[cc][rr] = A[(size_t)rowidx[rr] * D + k0 + cc];
      int rb = idx >> 6, cb = idx & 63;
      Bgs[rb][cb] = Bg[(size_t)(k0 + rb) * NI + bn + cb];
      Bus[rb][cb] = Bu[(size_t)(k0 + rb) * NI + bn + cb];
    }
    __syncthreads();
#pragma unroll
    for (int kk = 0; kk < 16; ++kk) {
      float a[4], bg[4], bu[4];
#pragma unroll
      for (int i = 0; i < 4; ++i) a[i] = As[kk][tr * 4 + i];
#pragma unroll
      for (int j = 0; j < 4; ++j) { bg[j] = Bgs[kk][tc * 4 + j]; bu[j] = Bus[kk][tc * 4 + j]; }
#pragma unroll
      for (int i = 0; i < 4; ++i)
#pragma unroll
        for (int j = 0; j < 4; ++j) { accg[i][j] += a[i] * bg[j]; accu[i][j] += a[i] * bu[j]; }
    }
    __syncthreads();
  }
#pragma unroll
  for (int i = 0; i < 4; ++i) {
    int pos = bm + tr * 4 + i;
    if (pos < cnt) {
#pragma unroll
      for (int j = 0; j < 4; ++j) {
        float g = accg[i][j], uu = accu[i][j];
        float sg = g / (1.f + __expf(-g));
        Cact[(size_t)(obase + pos) * NI + bn + tc * 4 + j] = sg * uu;
      }
    }
  }
}

// ------------------------------------- MoE down GEMM over compressed rows
__global__ void moe_down_kernel(const float* __restrict__ act, const float* __restrict__ Wd,
                                float* __restrict__ eo,
                                const int* __restrict__ counts, const int* __restrict__ offsets) {
  int e = blockIdx.z;
  int cnt = counts[e];
  int bm = blockIdx.y * 64;
  if (bm >= cnt) return;
  int bn = blockIdx.x * 64;
  int obase = offsets[e];
  const float* B = Wd + (size_t)e * NI * D;
  __shared__ float As[16][68];
  __shared__ float Bs[16][64];
  int tid = threadIdx.x;
  int tr = tid >> 4, tc = tid & 15;
  float acc[4][4] = {};
  for (int k0 = 0; k0 < NI; k0 += 16) {
#pragma unroll
    for (int i = 0; i < 4; ++i) {
      int idx = tid + i * 256;
      int rr = idx >> 4, cc = idx & 15;
      int pos = bm + rr;
      if (pos >= cnt) pos = cnt - 1;
      As[cc][rr] = act[(size_t)(obase + pos) * NI + k0 + cc];
      int rb = idx >> 6, cb = idx & 63;
      Bs[rb][cb] = B[(size_t)(k0 + rb) * D + bn + cb];
    }
    __syncthreads();
#pragma unroll
    for (int kk = 0; kk < 16; ++kk) {
      float a[4], b[4];
#pragma unroll
      for (int i = 0; i < 4; ++i) a[i] = As[kk][tr * 4 + i];
#pragma unroll
      for (int j = 0; j < 4; ++j) b[j] = Bs[kk][tc * 4 + j];
#pragma unroll
      for (int i = 0; i < 4; ++i)
#pragma unroll
        for (int j = 0; j < 4; ++j) acc[i][j] += a[i] * b[j];
    }
    __syncthreads();
  }
#pragma unroll
  for (int i = 0; i < 4; ++i) {
    int pos = bm + tr * 4 + i;
    if (pos < cnt) {
#pragma unroll
      for (int j = 0; j < 4; ++j)
        eo[(size_t)(obase + pos) * D + bn + tc * 4 + j] = acc[i][j];
    }
  }
}

// ---------------------------------------------------------------- final add
__global__ void final_kernel(const float* __restrict__ x, const float* __restrict__ sout,
                             const float* __restrict__ eo,
                             const int* __restrict__ topk_e, const int* __restrict__ topk_pos,
                             const float* __restrict__ topk_w, const int* __restrict__ offsets,
                             float* __restrict__ out) {
  int t = blockIdx.x;
  int tid = threadIdx.x;
  int e0 = topk_e[2 * t], e1 = topk_e[2 * t + 1];
  size_t r0 = (size_t)offsets[e0] + topk_pos[2 * t];
  size_t r1 = (size_t)offsets[e1] + topk_pos[2 * t + 1];
  float w0 = topk_w[2 * t], w1 = topk_w[2 * t + 1];
#pragma unroll
  for (int i = 0; i < 4; ++i) {
    int d = tid + i * 256;
    size_t idx = (size_t)t * D + d;
    out[idx] = x[idx] + sout[idx] + w0 * eo[r0 * D + d] + w1 * eo[r1 * D + d];
  }
}

extern "C" void kernel_launch(void* const* d_in, const int* in_sizes, int n_in,
                              void* d_out, int out_size, void* d_ws, size_t ws_size,
                              hipStream_t stream) {
  const float* hidden  = (const float*)d_in[0];
  const float* cosb    = (const float*)d_in[1];
  const float* sinb    = (const float*)d_in[2];
  const float* w_qkv   = (const float*)d_in[3];
  const float* w_o     = (const float*)d_in[4];
  const float* q_norm  = (const float*)d_in[5];
  const float* k_norm  = (const float*)d_in[6];
  const float* in_ln   = (const float*)d_in[7];
  const float* post_ln = (const float*)d_in[8];
  const float* router_w= (const float*)d_in[9];
  const float* w_gate  = (const float*)d_in[10];
  const float* w_up    = (const float*)d_in[11];
  const float* w_down  = (const float*)d_in[12];
  const float* ws_gate = (const float*)d_in[13];
  const float* ws_up   = (const float*)d_in[14];
  const float* ws_down = (const float*)d_in[15];
  float* out = (float*)d_out;
  float* ws = (float*)d_ws;

  const size_t M1 = 1048576;
  float* h    = ws;                        // 2M floats
  float* qkv  = ws + 2 * M1;               // 3M
  float* qb   = ws + 5 * M1;               // 2M
  float* kb   = ws + 7 * M1;               // 0.5M
  float* x    = ws + 7 * M1 + 524288;      // 2M
  float* h2   = x + 2 * M1;                // 2M
  float* act  = h2 + 2 * M1;               // 4M (compressed: total rows = 2*S)
  float* eo   = act + 4 * M1;              // 4M
  int* counts   = (int*)(eo + 4 * M1);
  int* offsets  = counts + NE;
  int* tok_list = offsets + NE;            // NE*S
  int* topk_e   = tok_list + NE * S;       // 2*S
  int* topk_pos = topk_e + 2 * S;          // 2*S
  float* topk_w = (float*)(topk_pos + 2 * S); // 2*S
  // aliases (lifetimes don't overlap):
  float* attnb = h;     // h dead after qkv GEMM
  float* sact  = qb;    // q dead after attention
  float* sout  = qkv;   // qkv (v) dead after attention

  dim3 b256(256);
  zero_counts_kernel<<<1, 64, 0, stream>>>(counts);
  rmsnorm_kernel<<<S, b256, 0, stream>>>(hidden, in_ln, h);
  gemm_kernel<<<dim3(QKV_N / 64, S / 64), b256, 0, stream>>>(h, w_qkv, nullptr, qkv, S, QKV_N, D);
  qkv_post_kernel<<<dim3(S, 5), b256, 0, stream>>>(qkv, q_norm, k_norm, cosb, sinb, qb, kb);
  attn_kernel<<<dim3(S / 32, NH), b256, 0, stream>>>(qb, kb, qkv, attnb);
  gemm_kernel<<<dim3(D / 64, S / 64), b256, 0, stream>>>(attnb, w_o, hidden, x, S, D, D);
  rmsnorm_kernel<<<S, b256, 0, stream>>>(x, post_ln, h2);
  router_kernel<<<S, 64, 0, stream>>>(h2, router_w, counts, tok_list, topk_e, topk_pos, topk_w);
  scan_kernel<<<1, 64, 0, stream>>>(counts, offsets);
  gu_kernel<<<dim3(NI / 64, S / 64, NE), b256, 0, stream>>>(h2, w_gate, w_up, act, tok_list, counts, offsets);
  moe_down_kernel<<<dim3(D / 64, S / 64, NE), b256, 0, stream>>>(act, w_down, eo, counts, offsets);
  gu_kernel<<<dim3(NI / 64, S / 64, 1), b256, 0, stream>>>(h2, ws_gate, ws_up, sact, nullptr, nullptr, nullptr);
  gemm_kernel<<<dim3(D / 64, S / 64), b256, 0, stream>>>(sact, ws_down, nullptr, sout, S, D, NI);
  final_kernel<<<S, b256, 0, stream>>>(x, sout, eo, topk_e, topk_pos, topk_w, offsets, out);
}

// Round 4
// 1590.633 us; speedup vs baseline: 1.2975x; 1.2975x over previous
//
#include <hip/hip_runtime.h>
#include <hip/hip_bf16.h>
#include <math.h>

#define S 2048
#define D 1024
#define NH 16
#define NKV 4
#define HD 64
#define QKV_N 1536          // (NH + 2*NKV) * HD
#define NE 8
#define NI 1024
#define EPS 1e-6f

typedef __bf16 bf16_t;
typedef __attribute__((ext_vector_type(8))) __bf16 bf16x8;
typedef __attribute__((ext_vector_type(4))) float f32x4;
union I4B8 { int4 i; bf16x8 v; };

// ---------------------------------------------------------------- rmsnorm(D)
// writes fp32 (optional) and bf16 (optional) outputs
__global__ void rmsnorm_kernel(const float* __restrict__ in, const float* __restrict__ w,
                               float* __restrict__ out32, __hip_bfloat16* __restrict__ out16) {
  int t = blockIdx.x;
  int tid = threadIdx.x;
  const float* row = in + (size_t)t * D;
  float v[4];
  float ss = 0.f;
#pragma unroll
  for (int i = 0; i < 4; ++i) {
    v[i] = row[tid + i * 256];
    ss += v[i] * v[i];
  }
#pragma unroll
  for (int off = 32; off; off >>= 1) ss += __shfl_xor(ss, off);
  __shared__ float wsum[4];
  int wave = tid >> 6;
  if ((tid & 63) == 0) wsum[wave] = ss;
  __syncthreads();
  float tot = wsum[0] + wsum[1] + wsum[2] + wsum[3];
  float r = rsqrtf(tot / (float)D + EPS);
#pragma unroll
  for (int i = 0; i < 4; ++i) {
    int d = tid + i * 256;
    float val = v[i] * r * w[d];
    if (out32) out32[(size_t)t * D + d] = val;
    if (out16) out16[(size_t)t * D + d] = __float2bfloat16(val);
  }
}

// ------------------------------------------- weight transpose + bf16 cast
// W fp32 [E][Kd][Nd]  ->  WT bf16 [E][Nd][Kd]
__global__ void transpose_cast_kernel(const float* __restrict__ W,
                                      __hip_bfloat16* __restrict__ WT, int Kd, int Nd) {
  __shared__ float tile[32][33];
  int e = blockIdx.z;
  const float* Wp = W + (size_t)e * Kd * Nd;
  __hip_bfloat16* WTp = WT + (size_t)e * Kd * Nd;
  int n0 = blockIdx.x * 32, k0 = blockIdx.y * 32;
  int tx = threadIdx.x & 31, ty = threadIdx.x >> 5;
#pragma unroll
  for (int i = 0; i < 4; ++i)
    tile[ty + i * 8][tx] = Wp[(size_t)(k0 + ty + i * 8) * Nd + n0 + tx];
  __syncthreads();
#pragma unroll
  for (int i = 0; i < 4; ++i)
    WTp[(size_t)(n0 + ty + i * 8) * Kd + k0 + tx] = __float2bfloat16(tile[tx][ty + i * 8]);
}

// ------------------------------------------- MFMA bf16 GEMM, 128x128 tile
// C[M,N](fp32) = A[M,K](bf16, optionally gathered/compressed rows) @ BT[N,K](bf16)^T (+Cadd)
__global__ __launch_bounds__(256) void mgemm_kernel(
    const __hip_bfloat16* __restrict__ A, const __hip_bfloat16* __restrict__ BT,
    const float* __restrict__ Cadd, float* __restrict__ C,
    int M, int N, int K,
    const int* __restrict__ counts, const int* __restrict__ offsets,
    const int* __restrict__ tok, int a_comp) {
  __shared__ int AsI[128 * 20];   // 128 rows x 32 bf16 (stride 40 bf16 = 20 ints)
  __shared__ int BsI[128 * 20];
  __shared__ int rowmap[128];
  int e = blockIdx.z;
  int cnt = counts ? counts[e] : M;
  int bm = blockIdx.y * 128;
  if (bm >= cnt) return;
  int bn = blockIdx.x * 128;
  int obase = offsets ? offsets[e] : 0;
  const bf16_t* Ab = (const bf16_t*)A;
  const bf16_t* BTe = (const bf16_t*)BT + (size_t)e * N * K;
  const int* toke = tok ? tok + e * S : nullptr;
  int tid = threadIdx.x;
  if (tid < 128) {
    int gp = bm + tid;
    int cp = gp < cnt ? gp : cnt - 1;
    rowmap[tid] = toke ? toke[cp] : (a_comp ? obase + cp : cp);
  }
  __syncthreads();
  int wave = tid >> 6, lane = tid & 63;
  int quad = lane >> 4, l16 = lane & 15;
  int wm = wave >> 1, wn = wave & 1;
  int p = tid >> 1, hf = tid & 1;
  f32x4 acc[4][4];
#pragma unroll
  for (int i = 0; i < 4; ++i)
#pragma unroll
    for (int j = 0; j < 4; ++j) acc[i][j] = (f32x4){0.f, 0.f, 0.f, 0.f};
  for (int k0 = 0; k0 < K; k0 += 32) {
    const int4* ga = (const int4*)(Ab + (size_t)rowmap[p] * K + k0 + hf * 16);
    int4 a0 = ga[0], a1 = ga[1];
    const int4* gb = (const int4*)(BTe + (size_t)(bn + p) * K + k0 + hf * 16);
    int4 b0 = gb[0], b1 = gb[1];
    *(int4*)&AsI[p * 20 + hf * 8] = a0;
    *(int4*)&AsI[p * 20 + hf * 8 + 4] = a1;
    *(int4*)&BsI[p * 20 + hf * 8] = b0;
    *(int4*)&BsI[p * 20 + hf * 8 + 4] = b1;
    __syncthreads();
    I4B8 af[4], bfr[4];
#pragma unroll
    for (int s = 0; s < 4; ++s)
      af[s].i = *(const int4*)&AsI[(wm * 64 + s * 16 + l16) * 20 + quad * 4];
#pragma unroll
    for (int s = 0; s < 4; ++s)
      bfr[s].i = *(const int4*)&BsI[(wn * 64 + s * 16 + l16) * 20 + quad * 4];
#pragma unroll
    for (int i = 0; i < 4; ++i)
#pragma unroll
      for (int j = 0; j < 4; ++j)
        acc[i][j] = __builtin_amdgcn_mfma_f32_16x16x32_bf16(af[i].v, bfr[j].v, acc[i][j], 0, 0, 0);
    __syncthreads();
  }
#pragma unroll
  for (int i = 0; i < 4; ++i) {
#pragma unroll
    for (int r = 0; r < 4; ++r) {
      int trow = wm * 64 + i * 16 + quad * 4 + r;   // C/D row = quad*4+reg
      int gp = bm + trow;
      if (gp < cnt) {
        size_t rowb = (size_t)(obase + gp) * N;
#pragma unroll
        for (int j = 0; j < 4; ++j) {
          int col = bn + wn * 64 + j * 16 + l16;    // C/D col = lane&15
          size_t idx = rowb + col;
          C[idx] = acc[i][j][r] + (Cadd ? Cadd[idx] : 0.f);
        }
      }
    }
  }
}

// ------------------------------------------- dual-B MFMA GEMM + silu epilogue
// act[row,:](bf16) = silu(A@BTg^T) * (A@BTu^T)
__global__ __launch_bounds__(256) void mgemm_gu_kernel(
    const __hip_bfloat16* __restrict__ A, const __hip_bfloat16* __restrict__ BTg,
    const __hip_bfloat16* __restrict__ BTu, __hip_bfloat16* __restrict__ act,
    int M, int N, int K,
    const int* __restrict__ counts, const int* __restrict__ offsets,
    const int* __restrict__ tok) {
  __shared__ int AsI[128 * 20];
  __shared__ int BgI[128 * 20];
  __shared__ int BuI[128 * 20];
  __shared__ int rowmap[128];
  int e = blockIdx.z;
  int cnt = counts ? counts[e] : M;
  int bm = blockIdx.y * 128;
  if (bm >= cnt) return;
  int bn = blockIdx.x * 128;
  int obase = offsets ? offsets[e] : 0;
  const bf16_t* Ab = (const bf16_t*)A;
  const bf16_t* Bg = (const bf16_t*)BTg + (size_t)e * N * K;
  const bf16_t* Bu = (const bf16_t*)BTu + (size_t)e * N * K;
  const int* toke = tok ? tok + e * S : nullptr;
  int tid = threadIdx.x;
  if (tid < 128) {
    int gp = bm + tid;
    int cp = gp < cnt ? gp : cnt - 1;
    rowmap[tid] = toke ? toke[cp] : cp;
  }
  __syncthreads();
  int wave = tid >> 6, lane = tid & 63;
  int quad = lane >> 4, l16 = lane & 15;
  int wm = wave >> 1, wn = wave & 1;
  int p = tid >> 1, hf = tid & 1;
  f32x4 accg[4][4], accu[4][4];
#pragma unroll
  for (int i = 0; i < 4; ++i)
#pragma unroll
    for (int j = 0; j < 4; ++j) {
      accg[i][j] = (f32x4){0.f, 0.f, 0.f, 0.f};
      accu[i][j] = (f32x4){0.f, 0.f, 0.f, 0.f};
    }
  for (int k0 = 0; k0 < K; k0 += 32) {
    const int4* ga = (const int4*)(Ab + (size_t)rowmap[p] * K + k0 + hf * 16);
    int4 a0 = ga[0], a1 = ga[1];
    const int4* gg = (const int4*)(Bg + (size_t)(bn + p) * K + k0 + hf * 16);
    int4 g0 = gg[0], g1 = gg[1];
    const int4* gu = (const int4*)(Bu + (size_t)(bn + p) * K + k0 + hf * 16);
    int4 u0 = gu[0], u1 = gu[1];
    *(int4*)&AsI[p * 20 + hf * 8] = a0;
    *(int4*)&AsI[p * 20 + hf * 8 + 4] = a1;
    *(int4*)&BgI[p * 20 + hf * 8] = g0;
    *(int4*)&BgI[p * 20 + hf * 8 + 4] = g1;
    *(int4*)&BuI[p * 20 + hf * 8] = u0;
    *(int4*)&BuI[p * 20 + hf * 8 + 4] = u1;
    __syncthreads();
    I4B8 af[4], bg[4], bu[4];
#pragma unroll
    for (int s = 0; s < 4; ++s)
      af[s].i = *(const int4*)&AsI[(wm * 64 + s * 16 + l16) * 20 + quad * 4];
#pragma unroll
    for (int s = 0; s < 4; ++s) {
      bg[s].i = *(const int4*)&BgI[(wn * 64 + s * 16 + l16) * 20 + quad * 4];
      bu[s].i = *(const int4*)&BuI[(wn * 64 + s * 16 + l16) * 20 + quad * 4];
    }
#pragma unroll
    for (int i = 0; i < 4; ++i)
#pragma unroll
      for (int j = 0; j < 4; ++j) {
        accg[i][j] = __builtin_amdgcn_mfma_f32_16x16x32_bf16(af[i].v, bg[j].v, accg[i][j], 0, 0, 0);
        accu[i][j] = __builtin_amdgcn_mfma_f32_16x16x32_bf16(af[i].v, bu[j].v, accu[i][j], 0, 0, 0);
      }
    __syncthreads();
  }
#pragma unroll
  for (int i = 0; i < 4; ++i) {
#pragma unroll
    for (int r = 0; r < 4; ++r) {
      int trow = wm * 64 + i * 16 + quad * 4 + r;
      int gp = bm + trow;
      if (gp < cnt) {
        size_t rowb = (size_t)(obase + gp) * N;
#pragma unroll
        for (int j = 0; j < 4; ++j) {
          int col = bn + wn * 64 + j * 16 + l16;
          float g = accg[i][j][r], uu = accu[i][j][r];
          float sg = g / (1.f + __expf(-g));
          act[rowb + col] = __float2bfloat16(sg * uu);
        }
      }
    }
  }
}

// --------------------------------------------- q/k head rmsnorm + RoPE (R1 verbatim)
__global__ void qkv_post_kernel(const float* __restrict__ qkv,
                                const float* __restrict__ qw, const float* __restrict__ kw,
                                const float* __restrict__ cosb, const float* __restrict__ sinb,
                                float* __restrict__ qout, float* __restrict__ kout) {
  int t = blockIdx.x;
  int u = blockIdx.y * 4 + (threadIdx.x >> 6);   // 0..19: 16 q heads then 4 k heads
  int lane = threadIdx.x & 63;
  bool isq = (u < NH);
  int h = isq ? u : (u - NH);
  size_t src = (size_t)t * QKV_N + (isq ? (h * HD) : (NH * HD + h * HD)) + lane;
  float xv = qkv[src];
  float ss = xv * xv;
#pragma unroll
  for (int off = 32; off; off >>= 1) ss += __shfl_xor(ss, off);
  float r = rsqrtf(ss * (1.f / 64.f) + EPS);
  float xn = xv * r * (isq ? qw[lane] : kw[lane]);
  float other = __shfl_xor(xn, 32);
  float rot = (lane < 32) ? -other : other;
  float res = xn * cosb[t * 64 + lane] + rot * sinb[t * 64 + lane];
  if (isq) qout[(size_t)t * (NH * HD) + h * HD + lane] = res;
  else     kout[(size_t)t * (NKV * HD) + h * HD + lane] = res;
}

// --------------------------------------------- scalar flash attention (R1, bf16 out)
__global__ void attn_kernel(const float* __restrict__ q, const float* __restrict__ k,
                            const float* __restrict__ qkv, __hip_bfloat16* __restrict__ attn) {
  int qb = blockIdx.x, h = blockIdx.y;
  int kvh = h >> 2;                       // rep = 4
  __shared__ float Qs[32][65], Ks[32][65], Vs[32][65], Ss[32][33];
  __shared__ float mrow[32], lrow[32], arow[32];
  int tid = threadIdx.x;
  for (int i = tid; i < 32 * 64; i += 256) {
    int r = i >> 6, c = i & 63;
    Qs[r][c] = q[(size_t)(qb * 32 + r) * (NH * HD) + h * HD + c] * 0.125f;
  }
  if (tid < 32) { mrow[tid] = -1e30f; lrow[tid] = 0.f; }
  int r = tid >> 3;
  int cg = (tid & 7) * 8;
  float o[8] = {0, 0, 0, 0, 0, 0, 0, 0};
  __syncthreads();
  for (int kb = 0; kb <= qb; ++kb) {
    for (int i = tid; i < 32 * 64; i += 256) {
      int rr = i >> 6, c = i & 63;
      Ks[rr][c] = k[(size_t)(kb * 32 + rr) * (NKV * HD) + kvh * HD + c];
      Vs[rr][c] = qkv[(size_t)(kb * 32 + rr) * QKV_N + (NH + NKV) * HD + kvh * HD + c];
    }
    __syncthreads();
    {
      int sr = tid >> 3, sc0 = (tid & 7) * 4;
#pragma unroll
      for (int j = 0; j < 4; ++j) {
        float acc = 0.f;
        for (int dd = 0; dd < 64; ++dd) acc += Qs[sr][dd] * Ks[sc0 + j][dd];
        Ss[sr][sc0 + j] = acc;
      }
    }
    __syncthreads();
    if (tid < 32) {
      float mold = mrow[tid];
      float mx = mold;
      for (int j = 0; j < 32; ++j) mx = fmaxf(mx, Ss[tid][j]);
      float alpha = __expf(mold - mx);
      float sum = 0.f;
      for (int j = 0; j < 32; ++j) {
        float pv = __expf(Ss[tid][j] - mx);
        Ss[tid][j] = pv;
        sum += pv;
      }
      lrow[tid] = lrow[tid] * alpha + sum;
      mrow[tid] = mx;
      arow[tid] = alpha;
    }
    __syncthreads();
    float al = arow[r];
#pragma unroll
    for (int c = 0; c < 8; ++c) {
      float acc = 0.f;
      for (int j = 0; j < 32; ++j) acc += Ss[r][j] * Vs[j][cg + c];
      o[c] = o[c] * al + acc;
    }
    __syncthreads();
  }
  float inv = 1.f / lrow[r];
#pragma unroll
  for (int c = 0; c < 8; ++c)
    attn[(size_t)(qb * 32 + r) * (NH * HD) + h * HD + cg + c] = __float2bfloat16(o[c] * inv);
}

// ---------------------------------------------------------------- router
__global__ void zero_counts_kernel(int* counts) {
  if (threadIdx.x < NE) counts[threadIdx.x] = 0;
}

__global__ void router_kernel(const float* __restrict__ h2, const float* __restrict__ rw,
                              int* counts, int* tok_list, int* topk_e, int* topk_pos,
                              float* topk_w) {
  int t = blockIdx.x;
  int lane = threadIdx.x;   // 64
  float p[NE] = {};
  for (int d = lane; d < D; d += 64) {
    float hv = h2[(size_t)t * D + d];
#pragma unroll
    for (int e = 0; e < NE; ++e) p[e] += hv * rw[d * NE + e];
  }
#pragma unroll
  for (int off = 32; off; off >>= 1)
#pragma unroll
    for (int e = 0; e < NE; ++e) p[e] += __shfl_xor(p[e], off);
  if (lane == 0) {
    float mx = p[0];
#pragma unroll
    for (int e = 1; e < NE; ++e) mx = fmaxf(mx, p[e]);
    float ex[NE];
#pragma unroll
    for (int e = 0; e < NE; ++e) ex[e] = __expf(p[e] - mx);
    int e0 = 0;
#pragma unroll
    for (int e = 1; e < NE; ++e) if (ex[e] > ex[e0]) e0 = e;
    int e1 = (e0 == 0) ? 1 : 0;
#pragma unroll
    for (int e = 0; e < NE; ++e) if (e != e0 && ex[e] > ex[e1]) e1 = e;
    float w0 = ex[e0] / (ex[e0] + ex[e1]);
    float w1 = ex[e1] / (ex[e0] + ex[e1]);
    int pos0 = atomicAdd(&counts[e0], 1);
    int pos1 = atomicAdd(&counts[e1], 1);
    tok_list[e0 * S + pos0] = t;
    tok_list[e1 * S + pos1] = t;
    topk_e[2 * t] = e0;  topk_e[2 * t + 1] = e1;
    topk_pos[2 * t] = pos0;  topk_pos[2 * t + 1] = pos1;
    topk_w[2 * t] = w0;  topk_w[2 * t + 1] = w1;
  }
}

__global__ void scan_kernel(const int* counts, int* offsets) {
  if (threadIdx.x == 0) {
    int acc = 0;
    for (int e = 0; e < NE; ++e) { offsets[e] = acc; acc += counts[e]; }
  }
}

// ---------------------------------------------------------------- final add
__global__ void final_kernel(const float* __restrict__ x, const float* __restrict__ sout,
                             const float* __restrict__ eo,
                             const int* __restrict__ topk_e, const int* __restrict__ topk_pos,
                             const float* __restrict__ topk_w, const int* __restrict__ offsets,
                             float* __restrict__ out) {
  int t = blockIdx.x;
  int tid = threadIdx.x;
  int e0 = topk_e[2 * t], e1 = topk_e[2 * t + 1];
  size_t r0 = (size_t)offsets[e0] + topk_pos[2 * t];
  size_t r1 = (size_t)offsets[e1] + topk_pos[2 * t + 1];
  float w0 = topk_w[2 * t], w1 = topk_w[2 * t + 1];
#pragma unroll
  for (int i = 0; i < 4; ++i) {
    int d = tid + i * 256;
    size_t idx = (size_t)t * D + d;
    out[idx] = x[idx] + sout[idx] + w0 * eo[r0 * D + d] + w1 * eo[r1 * D + d];
  }
}

extern "C" void kernel_launch(void* const* d_in, const int* in_sizes, int n_in,
                              void* d_out, int out_size, void* d_ws, size_t ws_size,
                              hipStream_t stream) {
  const float* hidden  = (const float*)d_in[0];
  const float* cosb    = (const float*)d_in[1];
  const float* sinb    = (const float*)d_in[2];
  const float* w_qkv   = (const float*)d_in[3];
  const float* w_o     = (const float*)d_in[4];
  const float* q_norm  = (const float*)d_in[5];
  const float* k_norm  = (const float*)d_in[6];
  const float* in_ln   = (const float*)d_in[7];
  const float* post_ln = (const float*)d_in[8];
  const float* router_w= (const float*)d_in[9];
  const float* w_gate  = (const float*)d_in[10];
  const float* w_up    = (const float*)d_in[11];
  const float* w_down  = (const float*)d_in[12];
  const float* ws_gate = (const float*)d_in[13];
  const float* ws_up   = (const float*)d_in[14];
  const float* ws_down = (const float*)d_in[15];
  float* out = (float*)d_out;
  float* ws = (float*)d_ws;

  typedef __hip_bfloat16 hbf;
  const size_t M1 = 1048576;
  // weights (bf16), persistent across the call
  hbf* wqkvT = (hbf*)(ws);                      // 1.5M el
  hbf* woT   = (hbf*)(ws +  768 * 1024);        // 1M el
  hbf* wgT   = (hbf*)(ws + 1280 * 1024);        // 8M el
  hbf* wuT   = (hbf*)(ws + 5376 * 1024);        // 8M el
  hbf* wdT   = (hbf*)(ws + 9472 * 1024);        // 8M el
  hbf* wsgT  = (hbf*)(ws + 13568 * 1024);       // 1M el
  hbf* wsuT  = (hbf*)(ws + 14080 * 1024);       // 1M el
  hbf* wsdT  = (hbf*)(ws + 14592 * 1024);       // 1M el
  // activations
  hbf*   hb      = (hbf*)(ws + 15104 * 1024);   // 2M el (1M fl)  [15104K,16128K)
  float* qkv     = ws + 16128 * 1024;           // 3M fl          [16128K,19200K)
  float* qb      = ws + 19200 * 1024;           // 2M fl          [19200K,21248K)
  float* kb      = ws + 21248 * 1024;           // 0.5M fl        [21248K,21760K)
  hbf*   attnb16 = (hbf*)(ws + 21760 * 1024);   // 2M el (1M fl)  [21760K,22784K)
  float* x       = ws + 22784 * 1024;           // 2M fl
  float* h2      = ws + 24832 * 1024;           // 2M fl
  hbf*   h2b     = (hbf*)(ws + 26880 * 1024);   // 2M el (1M fl)
  // act/eo alias the dead qkv/qb/kb/attnb16 region (dead after w_o GEMM)
  hbf*   act     = (hbf*)(ws + 16128 * 1024);   // 4M el (2M fl)  [16128K,18176K)
  float* eo      = ws + 18176 * 1024;           // 4M fl          [18176K,22272K) < 22784K ok
  hbf*   sact    = (hbf*)(ws + 27904 * 1024);   // 2M el (1M fl)
  float* sout    = ws + 28928 * 1024;           // 2M fl
  int* counts   = (int*)(ws + 30976 * 1024);
  int* offsets  = counts + NE;
  int* tok_list = offsets + NE;                 // NE*S
  int* topk_e   = tok_list + NE * S;
  int* topk_pos = topk_e + 2 * S;
  float* topk_w = (float*)(topk_pos + 2 * S);

  dim3 b256(256);
  zero_counts_kernel<<<1, 64, 0, stream>>>(counts);
  // weight cast+transpose
  transpose_cast_kernel<<<dim3(QKV_N/32, D/32, 1), b256, 0, stream>>>(w_qkv, wqkvT, D, QKV_N);
  transpose_cast_kernel<<<dim3(D/32, D/32, 1),     b256, 0, stream>>>(w_o, woT, D, D);
  transpose_cast_kernel<<<dim3(NI/32, D/32, NE),   b256, 0, stream>>>(w_gate, wgT, D, NI);
  transpose_cast_kernel<<<dim3(NI/32, D/32, NE),   b256, 0, stream>>>(w_up, wuT, D, NI);
  transpose_cast_kernel<<<dim3(D/32, NI/32, NE),   b256, 0, stream>>>(w_down, wdT, NI, D);
  transpose_cast_kernel<<<dim3(NI/32, D/32, 1),    b256, 0, stream>>>(ws_gate, wsgT, D, NI);
  transpose_cast_kernel<<<dim3(NI/32, D/32, 1),    b256, 0, stream>>>(ws_up, wsuT, D, NI);
  transpose_cast_kernel<<<dim3(D/32, NI/32, 1),    b256, 0, stream>>>(ws_down, wsdT, NI, D);
  // attention block
  rmsnorm_kernel<<<S, b256, 0, stream>>>(hidden, in_ln, nullptr, hb);
  mgemm_kernel<<<dim3(QKV_N/128, S/128, 1), b256, 0, stream>>>(hb, wqkvT, nullptr, qkv,
      S, QKV_N, D, nullptr, nullptr, nullptr, 0);
  qkv_post_kernel<<<dim3(S, 5), b256, 0, stream>>>(qkv, q_norm, k_norm, cosb, sinb, qb, kb);
  attn_kernel<<<dim3(S/32, NH), b256, 0, stream>>>(qb, kb, qkv, attnb16);
  mgemm_kernel<<<dim3(D/128, S/128, 1), b256, 0, stream>>>(attnb16, woT, hidden, x,
      S, D, D, nullptr, nullptr, nullptr, 0);
  // MoE block
  rmsnorm_kernel<<<S, b256, 0, stream>>>(x, post_ln, h2, h2b);
  router_kernel<<<S, 64, 0, stream>>>(h2, router_w, counts, tok_list, topk_e, topk_pos, topk_w);
  scan_kernel<<<1, 64, 0, stream>>>(counts, offsets);
  mgemm_gu_kernel<<<dim3(NI/128, S/128, NE), b256, 0, stream>>>(h2b, wgT, wuT, act,
      S, NI, D, counts, offsets, tok_list);
  mgemm_kernel<<<dim3(D/128, S/128, NE), b256, 0, stream>>>(act, wdT, nullptr, eo,
      S, D, NI, counts, offsets, nullptr, 1);
  mgemm_gu_kernel<<<dim3(NI/128, S/128, 1), b256, 0, stream>>>(h2b, wsgT, wsuT, sact,
      S, NI, D, nullptr, nullptr, nullptr);
  mgemm_kernel<<<dim3(D/128, S/128, 1), b256, 0, stream>>>(sact, wsdT, nullptr, sout,
      S, D, NI, nullptr, nullptr, nullptr, 0);
  final_kernel<<<S, b256, 0, stream>>>(x, sout, eo, topk_e, topk_pos, topk_w, offsets, out);
}

// Round 5
// 685.106 us; speedup vs baseline: 3.0124x; 2.3217x over previous
//
#include <hip/hip_runtime.h>
#include <hip/hip_bf16.h>
#include <math.h>

#define S 2048
#define D 1024
#define NH 16
#define NKV 4
#define HD 64
#define QKV_N 1536          // (NH + 2*NKV) * HD
#define NE 8
#define NI 1024
#define EPS 1e-6f

typedef __bf16 bf16_t;
typedef __bf16 __attribute__((may_alias)) abf16;
typedef __attribute__((ext_vector_type(8))) __bf16 bf16x8;
typedef __attribute__((ext_vector_type(4))) float f32x4;
union I4B8 { int4 i; bf16x8 v; };

// ---------------------------------------------------------------- rmsnorm(D)
__global__ void rmsnorm_kernel(const float* __restrict__ in, const float* __restrict__ w,
                               float* __restrict__ out32, __hip_bfloat16* __restrict__ out16) {
  int t = blockIdx.x;
  int tid = threadIdx.x;
  const float* row = in + (size_t)t * D;
  float v[4];
  float ss = 0.f;
#pragma unroll
  for (int i = 0; i < 4; ++i) {
    v[i] = row[tid + i * 256];
    ss += v[i] * v[i];
  }
#pragma unroll
  for (int off = 32; off; off >>= 1) ss += __shfl_xor(ss, off);
  __shared__ float wsum[4];
  int wave = tid >> 6;
  if ((tid & 63) == 0) wsum[wave] = ss;
  __syncthreads();
  float tot = wsum[0] + wsum[1] + wsum[2] + wsum[3];
  float r = rsqrtf(tot / (float)D + EPS);
#pragma unroll
  for (int i = 0; i < 4; ++i) {
    int d = tid + i * 256;
    float val = v[i] * r * w[d];
    if (out32) out32[(size_t)t * D + d] = val;
    if (out16) out16[(size_t)t * D + d] = __float2bfloat16(val);
  }
}

// ------------------------------------------- weight transpose + bf16 cast
__global__ void transpose_cast_kernel(const float* __restrict__ W,
                                      __hip_bfloat16* __restrict__ WT, int Kd, int Nd) {
  __shared__ float tile[32][33];
  int e = blockIdx.z;
  const float* Wp = W + (size_t)e * Kd * Nd;
  __hip_bfloat16* WTp = WT + (size_t)e * Kd * Nd;
  int n0 = blockIdx.x * 32, k0 = blockIdx.y * 32;
  int tx = threadIdx.x & 31, ty = threadIdx.x >> 5;
#pragma unroll
  for (int i = 0; i < 4; ++i)
    tile[ty + i * 8][tx] = Wp[(size_t)(k0 + ty + i * 8) * Nd + n0 + tx];
  __syncthreads();
#pragma unroll
  for (int i = 0; i < 4; ++i)
    WTp[(size_t)(n0 + ty + i * 8) * Kd + k0 + tx] = __float2bfloat16(tile[tx][ty + i * 8]);
}

// ------------------------------------------- MFMA bf16 GEMM, 128x128 tile (verified R4)
__global__ __launch_bounds__(256) void mgemm_kernel(
    const __hip_bfloat16* __restrict__ A, const __hip_bfloat16* __restrict__ BT,
    const float* __restrict__ Cadd, float* __restrict__ C,
    int M, int N, int K,
    const int* __restrict__ counts, const int* __restrict__ offsets,
    const int* __restrict__ tok, int a_comp) {
  __shared__ int AsI[128 * 20];
  __shared__ int BsI[128 * 20];
  __shared__ int rowmap[128];
  int e = blockIdx.z;
  int cnt = counts ? counts[e] : M;
  int bm = blockIdx.y * 128;
  if (bm >= cnt) return;
  int bn = blockIdx.x * 128;
  int obase = offsets ? offsets[e] : 0;
  const bf16_t* Ab = (const bf16_t*)A;
  const bf16_t* BTe = (const bf16_t*)BT + (size_t)e * N * K;
  const int* toke = tok ? tok + e * S : nullptr;
  int tid = threadIdx.x;
  if (tid < 128) {
    int gp = bm + tid;
    int cp = gp < cnt ? gp : cnt - 1;
    rowmap[tid] = toke ? toke[cp] : (a_comp ? obase + cp : cp);
  }
  __syncthreads();
  int wave = tid >> 6, lane = tid & 63;
  int quad = lane >> 4, l16 = lane & 15;
  int wm = wave >> 1, wn = wave & 1;
  int p = tid >> 1, hf = tid & 1;
  f32x4 acc[4][4];
#pragma unroll
  for (int i = 0; i < 4; ++i)
#pragma unroll
    for (int j = 0; j < 4; ++j) acc[i][j] = (f32x4){0.f, 0.f, 0.f, 0.f};
  for (int k0 = 0; k0 < K; k0 += 32) {
    const int4* ga = (const int4*)(Ab + (size_t)rowmap[p] * K + k0 + hf * 16);
    int4 a0 = ga[0], a1 = ga[1];
    const int4* gb = (const int4*)(BTe + (size_t)(bn + p) * K + k0 + hf * 16);
    int4 b0 = gb[0], b1 = gb[1];
    *(int4*)&AsI[p * 20 + hf * 8] = a0;
    *(int4*)&AsI[p * 20 + hf * 8 + 4] = a1;
    *(int4*)&BsI[p * 20 + hf * 8] = b0;
    *(int4*)&BsI[p * 20 + hf * 8 + 4] = b1;
    __syncthreads();
    I4B8 af[4], bfr[4];
#pragma unroll
    for (int s = 0; s < 4; ++s)
      af[s].i = *(const int4*)&AsI[(wm * 64 + s * 16 + l16) * 20 + quad * 4];
#pragma unroll
    for (int s = 0; s < 4; ++s)
      bfr[s].i = *(const int4*)&BsI[(wn * 64 + s * 16 + l16) * 20 + quad * 4];
#pragma unroll
    for (int i = 0; i < 4; ++i)
#pragma unroll
      for (int j = 0; j < 4; ++j)
        acc[i][j] = __builtin_amdgcn_mfma_f32_16x16x32_bf16(af[i].v, bfr[j].v, acc[i][j], 0, 0, 0);
    __syncthreads();
  }
#pragma unroll
  for (int i = 0; i < 4; ++i) {
#pragma unroll
    for (int r = 0; r < 4; ++r) {
      int trow = wm * 64 + i * 16 + quad * 4 + r;
      int gp = bm + trow;
      if (gp < cnt) {
        size_t rowb = (size_t)(obase + gp) * N;
#pragma unroll
        for (int j = 0; j < 4; ++j) {
          int col = bn + wn * 64 + j * 16 + l16;
          size_t idx = rowb + col;
          C[idx] = acc[i][j][r] + (Cadd ? Cadd[idx] : 0.f);
        }
      }
    }
  }
}

// ------------------------------------------- dual-B MFMA GEMM + silu epilogue (verified R4)
__global__ __launch_bounds__(256) void mgemm_gu_kernel(
    const __hip_bfloat16* __restrict__ A, const __hip_bfloat16* __restrict__ BTg,
    const __hip_bfloat16* __restrict__ BTu, __hip_bfloat16* __restrict__ act,
    int M, int N, int K,
    const int* __restrict__ counts, const int* __restrict__ offsets,
    const int* __restrict__ tok) {
  __shared__ int AsI[128 * 20];
  __shared__ int BgI[128 * 20];
  __shared__ int BuI[128 * 20];
  __shared__ int rowmap[128];
  int e = blockIdx.z;
  int cnt = counts ? counts[e] : M;
  int bm = blockIdx.y * 128;
  if (bm >= cnt) return;
  int bn = blockIdx.x * 128;
  int obase = offsets ? offsets[e] : 0;
  const bf16_t* Ab = (const bf16_t*)A;
  const bf16_t* Bg = (const bf16_t*)BTg + (size_t)e * N * K;
  const bf16_t* Bu = (const bf16_t*)BTu + (size_t)e * N * K;
  const int* toke = tok ? tok + e * S : nullptr;
  int tid = threadIdx.x;
  if (tid < 128) {
    int gp = bm + tid;
    int cp = gp < cnt ? gp : cnt - 1;
    rowmap[tid] = toke ? toke[cp] : cp;
  }
  __syncthreads();
  int wave = tid >> 6, lane = tid & 63;
  int quad = lane >> 4, l16 = lane & 15;
  int wm = wave >> 1, wn = wave & 1;
  int p = tid >> 1, hf = tid & 1;
  f32x4 accg[4][4], accu[4][4];
#pragma unroll
  for (int i = 0; i < 4; ++i)
#pragma unroll
    for (int j = 0; j < 4; ++j) {
      accg[i][j] = (f32x4){0.f, 0.f, 0.f, 0.f};
      accu[i][j] = (f32x4){0.f, 0.f, 0.f, 0.f};
    }
  for (int k0 = 0; k0 < K; k0 += 32) {
    const int4* ga = (const int4*)(Ab + (size_t)rowmap[p] * K + k0 + hf * 16);
    int4 a0 = ga[0], a1 = ga[1];
    const int4* gg = (const int4*)(Bg + (size_t)(bn + p) * K + k0 + hf * 16);
    int4 g0 = gg[0], g1 = gg[1];
    const int4* gu = (const int4*)(Bu + (size_t)(bn + p) * K + k0 + hf * 16);
    int4 u0 = gu[0], u1 = gu[1];
    *(int4*)&AsI[p * 20 + hf * 8] = a0;
    *(int4*)&AsI[p * 20 + hf * 8 + 4] = a1;
    *(int4*)&BgI[p * 20 + hf * 8] = g0;
    *(int4*)&BgI[p * 20 + hf * 8 + 4] = g1;
    *(int4*)&BuI[p * 20 + hf * 8] = u0;
    *(int4*)&BuI[p * 20 + hf * 8 + 4] = u1;
    __syncthreads();
    I4B8 af[4], bg[4], bu[4];
#pragma unroll
    for (int s = 0; s < 4; ++s)
      af[s].i = *(const int4*)&AsI[(wm * 64 + s * 16 + l16) * 20 + quad * 4];
#pragma unroll
    for (int s = 0; s < 4; ++s) {
      bg[s].i = *(const int4*)&BgI[(wn * 64 + s * 16 + l16) * 20 + quad * 4];
      bu[s].i = *(const int4*)&BuI[(wn * 64 + s * 16 + l16) * 20 + quad * 4];
    }
#pragma unroll
    for (int i = 0; i < 4; ++i)
#pragma unroll
      for (int j = 0; j < 4; ++j) {
        accg[i][j] = __builtin_amdgcn_mfma_f32_16x16x32_bf16(af[i].v, bg[j].v, accg[i][j], 0, 0, 0);
        accu[i][j] = __builtin_amdgcn_mfma_f32_16x16x32_bf16(af[i].v, bu[j].v, accu[i][j], 0, 0, 0);
      }
    __syncthreads();
  }
#pragma unroll
  for (int i = 0; i < 4; ++i) {
#pragma unroll
    for (int r = 0; r < 4; ++r) {
      int trow = wm * 64 + i * 16 + quad * 4 + r;
      int gp = bm + trow;
      if (gp < cnt) {
        size_t rowb = (size_t)(obase + gp) * N;
#pragma unroll
        for (int j = 0; j < 4; ++j) {
          int col = bn + wn * 64 + j * 16 + l16;
          float g = accg[i][j][r], uu = accu[i][j][r];
          float sg = g / (1.f + __expf(-g));
          act[rowb + col] = __float2bfloat16(sg * uu);
        }
      }
    }
  }
}

// --------------------------------------------- q/k head rmsnorm + RoPE + bf16 cast
// grid (S, 6): units 0..15 = q heads, 16..19 = k heads, 20..23 = v cast
__global__ void qkv_post_kernel(const float* __restrict__ qkv,
                                const float* __restrict__ qw, const float* __restrict__ kw,
                                const float* __restrict__ cosb, const float* __restrict__ sinb,
                                __hip_bfloat16* __restrict__ qout,
                                __hip_bfloat16* __restrict__ kout,
                                __hip_bfloat16* __restrict__ vout) {
  int t = blockIdx.x;
  int u = blockIdx.y * 4 + (threadIdx.x >> 6);
  int lane = threadIdx.x & 63;
  if (u >= NH + NKV) {                       // v: plain cast
    int h = u - NH - NKV;
    float xv = qkv[(size_t)t * QKV_N + (NH + NKV) * HD + h * HD + lane];
    vout[(size_t)t * (NKV * HD) + h * HD + lane] = __float2bfloat16(xv);
    return;
  }
  bool isq = (u < NH);
  int h = isq ? u : (u - NH);
  size_t src = (size_t)t * QKV_N + (isq ? (h * HD) : (NH * HD + h * HD)) + lane;
  float xv = qkv[src];
  float ss = xv * xv;
#pragma unroll
  for (int off = 32; off; off >>= 1) ss += __shfl_xor(ss, off);
  float r = rsqrtf(ss * (1.f / 64.f) + EPS);
  float xn = xv * r * (isq ? qw[lane] : kw[lane]);
  float other = __shfl_xor(xn, 32);
  float rot = (lane < 32) ? -other : other;
  float res = xn * cosb[t * 64 + lane] + rot * sinb[t * 64 + lane];
  if (isq) qout[(size_t)t * (NH * HD) + h * HD + lane] = __float2bfloat16(res * 0.125f);
  else     kout[(size_t)t * (NKV * HD) + h * HD + lane] = __float2bfloat16(res);
}

// --------------------------------------------- MFMA flash attention, mgemm-skeleton
// grid (S/64, NH), 256 thr (4 waves). Wave w owns q rows [qt*64+w*16, +16).
// All waves process all chunks uniformly; causally-dead chunks masked to -1e30.
__global__ __launch_bounds__(256) void attn_kernel(
    const __hip_bfloat16* __restrict__ qg, const __hip_bfloat16* __restrict__ kg,
    const __hip_bfloat16* __restrict__ vg, __hip_bfloat16* __restrict__ attn) {
  int qt = blockIdx.x, h = blockIdx.y;
  int kvh = h >> 2;
  int tid = threadIdx.x;
  int wave = tid >> 6, lane = tid & 63;
  int quad = lane >> 4, l16 = lane & 15;

  __shared__ __align__(16) int QsI[64 * 36];   // 64 q-rows x 64 bf16, stride 36 ints
  __shared__ __align__(16) int KsI[32 * 36];   // 32 keys x 64 bf16
  __shared__ __align__(16) int VsI[32 * 36];
  __shared__ __align__(16) int PsI[4][16 * 20]; // per-wave P: 16 rows x 32 bf16, stride 20 ints

  // ---- stage Q tile (global -> LDS, int4), then frag read (mgemm A pattern)
  {
    int p = tid >> 2, c = (tid & 3) * 8;
    const int4* g = (const int4*)((const int*)qg + (size_t)(qt * 64 + p) * 512 + h * 32 + c);
    int4 v0 = g[0], v1 = g[1];
    *(int4*)&QsI[p * 36 + c] = v0;
    *(int4*)&QsI[p * 36 + c + 4] = v1;
  }
  __syncthreads();
  I4B8 qf[2];
#pragma unroll
  for (int ch = 0; ch < 2; ++ch)
    qf[ch].i = *(const int4*)&QsI[(wave * 16 + l16) * 36 + ch * 16 + quad * 4];

  float m_r[4], l_r[4];
  f32x4 o[4];
#pragma unroll
  for (int r = 0; r < 4; ++r) { m_r[r] = -1e30f; l_r[r] = 0.f; }
#pragma unroll
  for (int s4 = 0; s4 < 4; ++s4) o[s4] = (f32x4){0.f, 0.f, 0.f, 0.f};

  int myblk = qt * 2 + (wave >> 1);   // 32-block index of this wave's q rows
  int nkc = qt * 2 + 2;               // chunks 0 .. qt*2+1 (uniform across block)

  for (int kc = 0; kc < nkc; ++kc) {
    // ---- stage K,V chunk (32 keys x 64 bf16 each)
    {
      int p = tid >> 3, c = (tid & 7) * 4;
      int4 kk = *(const int4*)((const int*)kg + (size_t)(kc * 32 + p) * 128 + kvh * 32 + c);
      int4 vv = *(const int4*)((const int*)vg + (size_t)(kc * 32 + p) * 128 + kvh * 32 + c);
      *(int4*)&KsI[p * 36 + c] = kk;
      *(int4*)&VsI[p * 36 + c] = vv;
    }
    __syncthreads();
    // ---- QK^T: 16x32 scores per wave (2 subtiles of 16 keys)
    f32x4 s[2];
    s[0] = (f32x4){0.f, 0.f, 0.f, 0.f};
    s[1] = (f32x4){0.f, 0.f, 0.f, 0.f};
#pragma unroll
    for (int sub = 0; sub < 2; ++sub) {
#pragma unroll
      for (int ch = 0; ch < 2; ++ch) {
        I4B8 bu;
        bu.i = *(const int4*)&KsI[(sub * 16 + l16) * 36 + ch * 16 + quad * 4];
        s[sub] = __builtin_amdgcn_mfma_f32_16x16x32_bf16(qf[ch].v, bu.v, s[sub], 0, 0, 0);
      }
    }
    bool live = (kc <= myblk);        // wave-uniform
    // ---- online softmax (C layout: row=quad*4+r, col=l16)
    abf16* pw = (abf16*)PsI[wave];
    float al[4];
#pragma unroll
    for (int r = 0; r < 4; ++r) {
      float s0 = live ? s[0][r] : -1e30f;
      float s1 = live ? s[1][r] : -1e30f;
      float v = fmaxf(s0, s1);
#pragma unroll
      for (int off = 1; off < 16; off <<= 1) v = fmaxf(v, __shfl_xor(v, off));
      float mx = fmaxf(m_r[r], v);
      al[r] = __expf(m_r[r] - mx);
      m_r[r] = mx;
      float p0 = __expf(s0 - mx);
      float p1 = __expf(s1 - mx);
      float su = p0 + p1;
#pragma unroll
      for (int off = 1; off < 16; off <<= 1) su += __shfl_xor(su, off);
      l_r[r] = l_r[r] * al[r] + su;
      int prow = quad * 4 + r;
      pw[prow * 40 + l16] = (bf16_t)p0;
      pw[prow * 40 + 16 + l16] = (bf16_t)p1;
#pragma unroll
      for (int s4 = 0; s4 < 4; ++s4) o[s4][r] *= al[r];
    }
    __syncthreads();                  // P visible (full barrier, uniform)
    // ---- P A-fragment (mgemm A pattern): m=l16, k=quad*8+j
    I4B8 pu;
    pu.i = *(const int4*)&PsI[wave][l16 * 20 + quad * 4];
    // ---- PV: V B-frag = V[k=key=quad*8+j][n=hd=sub*16+l16], rows stride 72 bf16
    const abf16* vsb = (const abf16*)VsI;
#pragma unroll
    for (int sub = 0; sub < 4; ++sub) {
      union { bf16_t e[8]; bf16x8 v; } vu;
#pragma unroll
      for (int j = 0; j < 8; ++j)
        vu.e[j] = vsb[(quad * 8 + j) * 72 + sub * 16 + l16];
      o[sub] = __builtin_amdgcn_mfma_f32_16x16x32_bf16(pu.v, vu.v, o[sub], 0, 0, 0);
    }
    __syncthreads();                  // protect Ks/Vs/Ps for next chunk
  }
  // ---- epilogue: normalize, store bf16
#pragma unroll
  for (int r = 0; r < 4; ++r) {
    float inv = 1.f / l_r[r];
    int row = qt * 64 + wave * 16 + quad * 4 + r;
#pragma unroll
    for (int sub = 0; sub < 4; ++sub)
      attn[(size_t)row * 1024 + h * 64 + sub * 16 + l16] =
          __float2bfloat16(o[sub][r] * inv);
  }
}

// ---------------------------------------------------------------- router
__global__ void zero_counts_kernel(int* counts) {
  if (threadIdx.x < NE) counts[threadIdx.x] = 0;
}

__global__ void router_kernel(const float* __restrict__ h2, const float* __restrict__ rw,
                              int* counts, int* tok_list, int* topk_e, int* topk_pos,
                              float* topk_w) {
  int t = blockIdx.x;
  int lane = threadIdx.x;   // 64
  float p[NE] = {};
  for (int d = lane; d < D; d += 64) {
    float hv = h2[(size_t)t * D + d];
#pragma unroll
    for (int e = 0; e < NE; ++e) p[e] += hv * rw[d * NE + e];
  }
#pragma unroll
  for (int off = 32; off; off >>= 1)
#pragma unroll
    for (int e = 0; e < NE; ++e) p[e] += __shfl_xor(p[e], off);
  if (lane == 0) {
    float mx = p[0];
#pragma unroll
    for (int e = 1; e < NE; ++e) mx = fmaxf(mx, p[e]);
    float ex[NE];
#pragma unroll
    for (int e = 0; e < NE; ++e) ex[e] = __expf(p[e] - mx);
    int e0 = 0;
#pragma unroll
    for (int e = 1; e < NE; ++e) if (ex[e] > ex[e0]) e0 = e;
    int e1 = (e0 == 0) ? 1 : 0;
#pragma unroll
    for (int e = 0; e < NE; ++e) if (e != e0 && ex[e] > ex[e1]) e1 = e;
    float w0 = ex[e0] / (ex[e0] + ex[e1]);
    float w1 = ex[e1] / (ex[e0] + ex[e1]);
    int pos0 = atomicAdd(&counts[e0], 1);
    int pos1 = atomicAdd(&counts[e1], 1);
    tok_list[e0 * S + pos0] = t;
    tok_list[e1 * S + pos1] = t;
    topk_e[2 * t] = e0;  topk_e[2 * t + 1] = e1;
    topk_pos[2 * t] = pos0;  topk_pos[2 * t + 1] = pos1;
    topk_w[2 * t] = w0;  topk_w[2 * t + 1] = w1;
  }
}

__global__ void scan_kernel(const int* counts, int* offsets) {
  if (threadIdx.x == 0) {
    int acc = 0;
    for (int e = 0; e < NE; ++e) { offsets[e] = acc; acc += counts[e]; }
  }
}

// ---------------------------------------------------------------- final add
__global__ void final_kernel(const float* __restrict__ x, const float* __restrict__ sout,
                             const float* __restrict__ eo,
                             const int* __restrict__ topk_e, const int* __restrict__ topk_pos,
                             const float* __restrict__ topk_w, const int* __restrict__ offsets,
                             float* __restrict__ out) {
  int t = blockIdx.x;
  int tid = threadIdx.x;
  int e0 = topk_e[2 * t], e1 = topk_e[2 * t + 1];
  size_t r0 = (size_t)offsets[e0] + topk_pos[2 * t];
  size_t r1 = (size_t)offsets[e1] + topk_pos[2 * t + 1];
  float w0 = topk_w[2 * t], w1 = topk_w[2 * t + 1];
#pragma unroll
  for (int i = 0; i < 4; ++i) {
    int d = tid + i * 256;
    size_t idx = (size_t)t * D + d;
    out[idx] = x[idx] + sout[idx] + w0 * eo[r0 * D + d] + w1 * eo[r1 * D + d];
  }
}

extern "C" void kernel_launch(void* const* d_in, const int* in_sizes, int n_in,
                              void* d_out, int out_size, void* d_ws, size_t ws_size,
                              hipStream_t stream) {
  const float* hidden  = (const float*)d_in[0];
  const float* cosb    = (const float*)d_in[1];
  const float* sinb    = (const float*)d_in[2];
  const float* w_qkv   = (const float*)d_in[3];
  const float* w_o     = (const float*)d_in[4];
  const float* q_norm  = (const float*)d_in[5];
  const float* k_norm  = (const float*)d_in[6];
  const float* in_ln   = (const float*)d_in[7];
  const float* post_ln = (const float*)d_in[8];
  const float* router_w= (const float*)d_in[9];
  const float* w_gate  = (const float*)d_in[10];
  const float* w_up    = (const float*)d_in[11];
  const float* w_down  = (const float*)d_in[12];
  const float* ws_gate = (const float*)d_in[13];
  const float* ws_up   = (const float*)d_in[14];
  const float* ws_down = (const float*)d_in[15];
  float* out = (float*)d_out;
  float* ws = (float*)d_ws;

  typedef __hip_bfloat16 hbf;
  // weights (bf16)
  hbf* wqkvT = (hbf*)(ws);                      // 1.5M el
  hbf* woT   = (hbf*)(ws +  768 * 1024);        // 1M el
  hbf* wgT   = (hbf*)(ws + 1280 * 1024);        // 8M el
  hbf* wuT   = (hbf*)(ws + 5376 * 1024);        // 8M el
  hbf* wdT   = (hbf*)(ws + 9472 * 1024);        // 8M el
  hbf* wsgT  = (hbf*)(ws + 13568 * 1024);       // 1M el
  hbf* wsuT  = (hbf*)(ws + 14080 * 1024);       // 1M el
  hbf* wsdT  = (hbf*)(ws + 14592 * 1024);       // 1M el
  // activations
  hbf*   hb      = (hbf*)(ws + 15104 * 1024);   // [15104K,16128K)
  float* qkv     = ws + 16128 * 1024;           // [16128K,19200K)
  hbf*   qbB     = (hbf*)(ws + 19200 * 1024);   // 2M el  [19200K,20224K)
  hbf*   kbB     = (hbf*)(ws + 20224 * 1024);   // 512K el [20224K,20480K)
  hbf*   vbB     = (hbf*)(ws + 20480 * 1024);   // 512K el [20480K,20736K)
  hbf*   attnb16 = (hbf*)(ws + 20736 * 1024);   // 2M el  [20736K,21760K)
  float* x       = ws + 22784 * 1024;           // 2M fl
  float* h2      = ws + 24832 * 1024;           // 2M fl
  hbf*   h2b     = (hbf*)(ws + 26880 * 1024);   // 2M el
  hbf*   act     = (hbf*)(ws + 16128 * 1024);   // aliases qkv (dead after qkv_post)
  float* eo      = ws + 18176 * 1024;           // [18176K,22272K) aliases q/k/v/attnb16 (dead)
  hbf*   sact    = (hbf*)(ws + 27904 * 1024);
  float* sout    = ws + 28928 * 1024;
  int* counts   = (int*)(ws + 30976 * 1024);
  int* offsets  = counts + NE;
  int* tok_list = offsets + NE;
  int* topk_e   = tok_list + NE * S;
  int* topk_pos = topk_e + 2 * S;
  float* topk_w = (float*)(topk_pos + 2 * S);

  dim3 b256(256);
  zero_counts_kernel<<<1, 64, 0, stream>>>(counts);
  transpose_cast_kernel<<<dim3(QKV_N/32, D/32, 1), b256, 0, stream>>>(w_qkv, wqkvT, D, QKV_N);
  transpose_cast_kernel<<<dim3(D/32, D/32, 1),     b256, 0, stream>>>(w_o, woT, D, D);
  transpose_cast_kernel<<<dim3(NI/32, D/32, NE),   b256, 0, stream>>>(w_gate, wgT, D, NI);
  transpose_cast_kernel<<<dim3(NI/32, D/32, NE),   b256, 0, stream>>>(w_up, wuT, D, NI);
  transpose_cast_kernel<<<dim3(D/32, NI/32, NE),   b256, 0, stream>>>(w_down, wdT, NI, D);
  transpose_cast_kernel<<<dim3(NI/32, D/32, 1),    b256, 0, stream>>>(ws_gate, wsgT, D, NI);
  transpose_cast_kernel<<<dim3(NI/32, D/32, 1),    b256, 0, stream>>>(ws_up, wsuT, D, NI);
  transpose_cast_kernel<<<dim3(D/32, NI/32, 1),    b256, 0, stream>>>(ws_down, wsdT, NI, D);
  // attention block
  rmsnorm_kernel<<<S, b256, 0, stream>>>(hidden, in_ln, nullptr, hb);
  mgemm_kernel<<<dim3(QKV_N/128, S/128, 1), b256, 0, stream>>>(hb, wqkvT, nullptr, qkv,
      S, QKV_N, D, nullptr, nullptr, nullptr, 0);
  qkv_post_kernel<<<dim3(S, 6), b256, 0, stream>>>(qkv, q_norm, k_norm, cosb, sinb, qbB, kbB, vbB);
  attn_kernel<<<dim3(S/64, NH), b256, 0, stream>>>(qbB, kbB, vbB, attnb16);
  mgemm_kernel<<<dim3(D/128, S/128, 1), b256, 0, stream>>>(attnb16, woT, hidden, x,
      S, D, D, nullptr, nullptr, nullptr, 0);
  // MoE block
  rmsnorm_kernel<<<S, b256, 0, stream>>>(x, post_ln, h2, h2b);
  router_kernel<<<S, 64, 0, stream>>>(h2, router_w, counts, tok_list, topk_e, topk_pos, topk_w);
  scan_kernel<<<1, 64, 0, stream>>>(counts, offsets);
  mgemm_gu_kernel<<<dim3(NI/128, S/128, NE), b256, 0, stream>>>(h2b, wgT, wuT, act,
      S, NI, D, counts, offsets, tok_list);
  mgemm_kernel<<<dim3(D/128, S/128, NE), b256, 0, stream>>>(act, wdT, nullptr, eo,
      S, D, NI, counts, offsets, nullptr, 1);
  mgemm_gu_kernel<<<dim3(NI/128, S/128, 1), b256, 0, stream>>>(h2b, wsgT, wsuT, sact,
      S, NI, D, nullptr, nullptr, nullptr);
  mgemm_kernel<<<dim3(D/128, S/128, 1), b256, 0, stream>>>(sact, wsdT, nullptr, sout,
      S, D, NI, nullptr, nullptr, nullptr, 0);
  final_kernel<<<S, b256, 0, stream>>>(x, sout, eo, topk_e, topk_pos, topk_w, offsets, out);
}

// Round 7
// 671.879 us; speedup vs baseline: 3.0717x; 1.0197x over previous
//
#include <hip/hip_runtime.h>
#include <hip/hip_bf16.h>
#include <math.h>

#define S 2048
#define D 1024
#define NH 16
#define NKV 4
#define HD 64
#define QKV_N 1536          // (NH + 2*NKV) * HD
#define NE 8
#define NI 1024
#define EPS 1e-6f

typedef __bf16 bf16_t;
typedef __bf16 __attribute__((may_alias)) abf16;
typedef __attribute__((ext_vector_type(8))) __bf16 bf16x8;
typedef __attribute__((ext_vector_type(4))) float f32x4;
union I4B8 { int4 i; bf16x8 v; };

// ---------------------------------------------------------------- rmsnorm(D)
__global__ void rmsnorm_kernel(const float* __restrict__ in, const float* __restrict__ w,
                               float* __restrict__ out32, __hip_bfloat16* __restrict__ out16) {
  int t = blockIdx.x;
  int tid = threadIdx.x;
  const float* row = in + (size_t)t * D;
  float v[4];
  float ss = 0.f;
#pragma unroll
  for (int i = 0; i < 4; ++i) {
    v[i] = row[tid + i * 256];
    ss += v[i] * v[i];
  }
#pragma unroll
  for (int off = 32; off; off >>= 1) ss += __shfl_xor(ss, off);
  __shared__ float wsum[4];
  int wave = tid >> 6;
  if ((tid & 63) == 0) wsum[wave] = ss;
  __syncthreads();
  float tot = wsum[0] + wsum[1] + wsum[2] + wsum[3];
  float r = rsqrtf(tot / (float)D + EPS);
#pragma unroll
  for (int i = 0; i < 4; ++i) {
    int d = tid + i * 256;
    float val = v[i] * r * w[d];
    if (out32) out32[(size_t)t * D + d] = val;
    if (out16) out16[(size_t)t * D + d] = __float2bfloat16(val);
  }
}

// ------------------------------------------- weight transpose + bf16 cast
__global__ void transpose_cast_kernel(const float* __restrict__ W,
                                      __hip_bfloat16* __restrict__ WT, int Kd, int Nd) {
  __shared__ float tile[32][33];
  int e = blockIdx.z;
  const float* Wp = W + (size_t)e * Kd * Nd;
  __hip_bfloat16* WTp = WT + (size_t)e * Kd * Nd;
  int n0 = blockIdx.x * 32, k0 = blockIdx.y * 32;
  int tx = threadIdx.x & 31, ty = threadIdx.x >> 5;
#pragma unroll
  for (int i = 0; i < 4; ++i)
    tile[ty + i * 8][tx] = Wp[(size_t)(k0 + ty + i * 8) * Nd + n0 + tx];
  __syncthreads();
#pragma unroll
  for (int i = 0; i < 4; ++i)
    WTp[(size_t)(n0 + ty + i * 8) * Kd + k0 + tx] = __float2bfloat16(tile[tx][ty + i * 8]);
}

// ------------------------------------------- MFMA bf16 GEMM, 128x128 tile (R4-verified)
__global__ __launch_bounds__(256) void mgemm_kernel(
    const __hip_bfloat16* __restrict__ A, const __hip_bfloat16* __restrict__ BT,
    const float* __restrict__ Cadd, float* __restrict__ C,
    int M, int N, int K,
    const int* __restrict__ counts, const int* __restrict__ offsets,
    const int* __restrict__ tok, int a_comp) {
  __shared__ int AsI[128 * 20];
  __shared__ int BsI[128 * 20];
  __shared__ int rowmap[128];
  int e = blockIdx.z;
  int cnt = counts ? counts[e] : M;
  int bm = blockIdx.y * 128;
  if (bm >= cnt) return;
  int bn = blockIdx.x * 128;
  int obase = offsets ? offsets[e] : 0;
  const bf16_t* Ab = (const bf16_t*)A;
  const bf16_t* BTe = (const bf16_t*)BT + (size_t)e * N * K;
  const int* toke = tok ? tok + e * S : nullptr;
  int tid = threadIdx.x;
  if (tid < 128) {
    int gp = bm + tid;
    int cp = gp < cnt ? gp : cnt - 1;
    rowmap[tid] = toke ? toke[cp] : (a_comp ? obase + cp : cp);
  }
  __syncthreads();
  int wave = tid >> 6, lane = tid & 63;
  int quad = lane >> 4, l16 = lane & 15;
  int wm = wave >> 1, wn = wave & 1;
  int p = tid >> 1, hf = tid & 1;
  f32x4 acc[4][4];
#pragma unroll
  for (int i = 0; i < 4; ++i)
#pragma unroll
    for (int j = 0; j < 4; ++j) acc[i][j] = (f32x4){0.f, 0.f, 0.f, 0.f};
  for (int k0 = 0; k0 < K; k0 += 32) {
    const int4* ga = (const int4*)(Ab + (size_t)rowmap[p] * K + k0 + hf * 16);
    int4 a0 = ga[0], a1 = ga[1];
    const int4* gb = (const int4*)(BTe + (size_t)(bn + p) * K + k0 + hf * 16);
    int4 b0 = gb[0], b1 = gb[1];
    *(int4*)&AsI[p * 20 + hf * 8] = a0;
    *(int4*)&AsI[p * 20 + hf * 8 + 4] = a1;
    *(int4*)&BsI[p * 20 + hf * 8] = b0;
    *(int4*)&BsI[p * 20 + hf * 8 + 4] = b1;
    __syncthreads();
    I4B8 af[4], bfr[4];
#pragma unroll
    for (int s = 0; s < 4; ++s)
      af[s].i = *(const int4*)&AsI[(wm * 64 + s * 16 + l16) * 20 + quad * 4];
#pragma unroll
    for (int s = 0; s < 4; ++s)
      bfr[s].i = *(const int4*)&BsI[(wn * 64 + s * 16 + l16) * 20 + quad * 4];
#pragma unroll
    for (int i = 0; i < 4; ++i)
#pragma unroll
      for (int j = 0; j < 4; ++j)
        acc[i][j] = __builtin_amdgcn_mfma_f32_16x16x32_bf16(af[i].v, bfr[j].v, acc[i][j], 0, 0, 0);
    __syncthreads();
  }
#pragma unroll
  for (int i = 0; i < 4; ++i) {
#pragma unroll
    for (int r = 0; r < 4; ++r) {
      int trow = wm * 64 + i * 16 + quad * 4 + r;
      int gp = bm + trow;
      if (gp < cnt) {
        size_t rowb = (size_t)(obase + gp) * N;
#pragma unroll
        for (int j = 0; j < 4; ++j) {
          int col = bn + wn * 64 + j * 16 + l16;
          size_t idx = rowb + col;
          C[idx] = acc[i][j][r] + (Cadd ? Cadd[idx] : 0.f);
        }
      }
    }
  }
}

// ------------------------------------------- dual-B MFMA GEMM + silu epilogue (R4-verified)
__global__ __launch_bounds__(256) void mgemm_gu_kernel(
    const __hip_bfloat16* __restrict__ A, const __hip_bfloat16* __restrict__ BTg,
    const __hip_bfloat16* __restrict__ BTu, __hip_bfloat16* __restrict__ act,
    int M, int N, int K,
    const int* __restrict__ counts, const int* __restrict__ offsets,
    const int* __restrict__ tok) {
  __shared__ int AsI[128 * 20];
  __shared__ int BgI[128 * 20];
  __shared__ int BuI[128 * 20];
  __shared__ int rowmap[128];
  int e = blockIdx.z;
  int cnt = counts ? counts[e] : M;
  int bm = blockIdx.y * 128;
  if (bm >= cnt) return;
  int bn = blockIdx.x * 128;
  int obase = offsets ? offsets[e] : 0;
  const bf16_t* Ab = (const bf16_t*)A;
  const bf16_t* Bg = (const bf16_t*)BTg + (size_t)e * N * K;
  const bf16_t* Bu = (const bf16_t*)BTu + (size_t)e * N * K;
  const int* toke = tok ? tok + e * S : nullptr;
  int tid = threadIdx.x;
  if (tid < 128) {
    int gp = bm + tid;
    int cp = gp < cnt ? gp : cnt - 1;
    rowmap[tid] = toke ? toke[cp] : cp;
  }
  __syncthreads();
  int wave = tid >> 6, lane = tid & 63;
  int quad = lane >> 4, l16 = lane & 15;
  int wm = wave >> 1, wn = wave & 1;
  int p = tid >> 1, hf = tid & 1;
  f32x4 accg[4][4], accu[4][4];
#pragma unroll
  for (int i = 0; i < 4; ++i)
#pragma unroll
    for (int j = 0; j < 4; ++j) {
      accg[i][j] = (f32x4){0.f, 0.f, 0.f, 0.f};
      accu[i][j] = (f32x4){0.f, 0.f, 0.f, 0.f};
    }
  for (int k0 = 0; k0 < K; k0 += 32) {
    const int4* ga = (const int4*)(Ab + (size_t)rowmap[p] * K + k0 + hf * 16);
    int4 a0 = ga[0], a1 = ga[1];
    const int4* gg = (const int4*)(Bg + (size_t)(bn + p) * K + k0 + hf * 16);
    int4 g0 = gg[0], g1 = gg[1];
    const int4* gu = (const int4*)(Bu + (size_t)(bn + p) * K + k0 + hf * 16);
    int4 u0 = gu[0], u1 = gu[1];
    *(int4*)&AsI[p * 20 + hf * 8] = a0;
    *(int4*)&AsI[p * 20 + hf * 8 + 4] = a1;
    *(int4*)&BgI[p * 20 + hf * 8] = g0;
    *(int4*)&BgI[p * 20 + hf * 8 + 4] = g1;
    *(int4*)&BuI[p * 20 + hf * 8] = u0;
    *(int4*)&BuI[p * 20 + hf * 8 + 4] = u1;
    __syncthreads();
    I4B8 af[4], bg[4], bu[4];
#pragma unroll
    for (int s = 0; s < 4; ++s)
      af[s].i = *(const int4*)&AsI[(wm * 64 + s * 16 + l16) * 20 + quad * 4];
#pragma unroll
    for (int s = 0; s < 4; ++s) {
      bg[s].i = *(const int4*)&BgI[(wn * 64 + s * 16 + l16) * 20 + quad * 4];
      bu[s].i = *(const int4*)&BuI[(wn * 64 + s * 16 + l16) * 20 + quad * 4];
    }
#pragma unroll
    for (int i = 0; i < 4; ++i)
#pragma unroll
      for (int j = 0; j < 4; ++j) {
        accg[i][j] = __builtin_amdgcn_mfma_f32_16x16x32_bf16(af[i].v, bg[j].v, accg[i][j], 0, 0, 0);
        accu[i][j] = __builtin_amdgcn_mfma_f32_16x16x32_bf16(af[i].v, bu[j].v, accu[i][j], 0, 0, 0);
      }
    __syncthreads();
  }
#pragma unroll
  for (int i = 0; i < 4; ++i) {
#pragma unroll
    for (int r = 0; r < 4; ++r) {
      int trow = wm * 64 + i * 16 + quad * 4 + r;
      int gp = bm + trow;
      if (gp < cnt) {
        size_t rowb = (size_t)(obase + gp) * N;
#pragma unroll
        for (int j = 0; j < 4; ++j) {
          int col = bn + wn * 64 + j * 16 + l16;
          float g = accg[i][j][r], uu = accu[i][j][r];
          float sg = g / (1.f + __expf(-g));
          act[rowb + col] = __float2bfloat16(sg * uu);
        }
      }
    }
  }
}

// --------------------------------------------- q/k head rmsnorm + RoPE + bf16 cast
__global__ void qkv_post_kernel(const float* __restrict__ qkv,
                                const float* __restrict__ qw, const float* __restrict__ kw,
                                const float* __restrict__ cosb, const float* __restrict__ sinb,
                                __hip_bfloat16* __restrict__ qout,
                                __hip_bfloat16* __restrict__ kout,
                                __hip_bfloat16* __restrict__ vout) {
  int t = blockIdx.x;
  int u = blockIdx.y * 4 + (threadIdx.x >> 6);
  int lane = threadIdx.x & 63;
  if (u >= NH + NKV) {                       // v: plain cast
    int h = u - NH - NKV;
    float xv = qkv[(size_t)t * QKV_N + (NH + NKV) * HD + h * HD + lane];
    vout[(size_t)t * (NKV * HD) + h * HD + lane] = __float2bfloat16(xv);
    return;
  }
  bool isq = (u < NH);
  int h = isq ? u : (u - NH);
  size_t src = (size_t)t * QKV_N + (isq ? (h * HD) : (NH * HD + h * HD)) + lane;
  float xv = qkv[src];
  float ss = xv * xv;
#pragma unroll
  for (int off = 32; off; off >>= 1) ss += __shfl_xor(ss, off);
  float r = rsqrtf(ss * (1.f / 64.f) + EPS);
  float xn = xv * r * (isq ? qw[lane] : kw[lane]);
  float other = __shfl_xor(xn, 32);
  float rot = (lane < 32) ? -other : other;
  float res = xn * cosb[t * 64 + lane] + rot * sinb[t * 64 + lane];
  if (isq) qout[(size_t)t * (NH * HD) + h * HD + lane] = __float2bfloat16(res * 0.125f);
  else     kout[(size_t)t * (NKV * HD) + h * HD + lane] = __float2bfloat16(res);
}

// --------------------------------------------- MFMA flash attention v2
// grid (S/32, NH) REVERSED qb, 128 thr (2 waves), wave owns 16 q rows.
// 32-row q-tile == mask block => NO masking at all.
__global__ __launch_bounds__(128) void attn_kernel(
    const __hip_bfloat16* __restrict__ qg, const __hip_bfloat16* __restrict__ kg,
    const __hip_bfloat16* __restrict__ vg, __hip_bfloat16* __restrict__ attn) {
  int qb = (int)(gridDim.x - 1) - (int)blockIdx.x;   // heavy blocks first
  int h = blockIdx.y;
  int kvh = h >> 2;
  int tid = threadIdx.x;
  int wave = tid >> 6, lane = tid & 63;
  int quad = lane >> 4, l16 = lane & 15;

  __shared__ __align__(16) int QsI[32 * 36];   // 32 rows x 64 bf16, stride 36 ints
  __shared__ __align__(16) int KsI[32 * 36];
  __shared__ __align__(16) int VsI[32 * 34];   // stride 34 for u16 frag reads
  __shared__ __align__(16) int PsI[2][16 * 20];

  // stage Q (32 rows x 32 ints)
#pragma unroll
  for (int i = 0; i < 2; ++i) {
    int idx = tid + i * 128;
    int p = idx >> 3, c = (idx & 7) * 4;
    *(int4*)&QsI[p * 36 + c] =
        *(const int4*)((const int*)qg + (size_t)(qb * 32 + p) * 512 + h * 32 + c);
  }
  __syncthreads();
  I4B8 qf[2];
#pragma unroll
  for (int ch = 0; ch < 2; ++ch)
    qf[ch].i = *(const int4*)&QsI[(wave * 16 + l16) * 36 + ch * 16 + quad * 4];

  float m_r[4], l_r[4];
  f32x4 o[4];
#pragma unroll
  for (int r = 0; r < 4; ++r) { m_r[r] = -1e30f; l_r[r] = 0.f; }
#pragma unroll
  for (int s4 = 0; s4 < 4; ++s4) o[s4] = (f32x4){0.f, 0.f, 0.f, 0.f};

  for (int kc = 0; kc <= qb; ++kc) {
    // stage K (int4, stride 36) and V (int2, stride 34)
#pragma unroll
    for (int i = 0; i < 2; ++i) {
      int idx = tid + i * 128;
      int p = idx >> 3, c = (idx & 7) * 4;
      *(int4*)&KsI[p * 36 + c] =
          *(const int4*)((const int*)kg + (size_t)(kc * 32 + p) * 128 + kvh * 32 + c);
    }
#pragma unroll
    for (int i = 0; i < 4; ++i) {
      int idx = tid + i * 128;
      int p = idx >> 4, c = (idx & 15) * 2;
      *(int2*)&VsI[p * 34 + c] =
          *(const int2*)((const int*)vg + (size_t)(kc * 32 + p) * 128 + kvh * 32 + c);
    }
    __syncthreads();
    // ---- QK^T: 16x32 per wave
    f32x4 s[2];
    s[0] = (f32x4){0.f, 0.f, 0.f, 0.f};
    s[1] = (f32x4){0.f, 0.f, 0.f, 0.f};
#pragma unroll
    for (int sub = 0; sub < 2; ++sub) {
#pragma unroll
      for (int ch = 0; ch < 2; ++ch) {
        I4B8 bu;
        bu.i = *(const int4*)&KsI[(sub * 16 + l16) * 36 + ch * 16 + quad * 4];
        s[sub] = __builtin_amdgcn_mfma_f32_16x16x32_bf16(qf[ch].v, bu.v, s[sub], 0, 0, 0);
      }
    }
    // ---- online softmax (no mask)
    abf16* pw = (abf16*)PsI[wave];
    float al[4];
#pragma unroll
    for (int r = 0; r < 4; ++r) {
      float v = fmaxf(s[0][r], s[1][r]);
#pragma unroll
      for (int off = 1; off < 16; off <<= 1) v = fmaxf(v, __shfl_xor(v, off));
      float mx = fmaxf(m_r[r], v);
      al[r] = __expf(m_r[r] - mx);
      m_r[r] = mx;
      float p0 = __expf(s[0][r] - mx);
      float p1 = __expf(s[1][r] - mx);
      float su = p0 + p1;
#pragma unroll
      for (int off = 1; off < 16; off <<= 1) su += __shfl_xor(su, off);
      l_r[r] = l_r[r] * al[r] + su;
      int prow = quad * 4 + r;
      pw[prow * 40 + l16] = (bf16_t)p0;
      pw[prow * 40 + 16 + l16] = (bf16_t)p1;
#pragma unroll
      for (int s4 = 0; s4 < 4; ++s4) o[s4][r] *= al[r];
    }
    __syncthreads();
    // ---- P A-frag + PV
    I4B8 pu;
    pu.i = *(const int4*)&PsI[wave][l16 * 20 + quad * 4];
    const abf16* vsb = (const abf16*)VsI;
#pragma unroll
    for (int sub = 0; sub < 4; ++sub) {
      union { bf16_t e[8]; bf16x8 v; } vu;
#pragma unroll
      for (int j = 0; j < 8; ++j)
        vu.e[j] = vsb[(quad * 8 + j) * 68 + sub * 16 + l16];
      o[sub] = __builtin_amdgcn_mfma_f32_16x16x32_bf16(pu.v, vu.v, o[sub], 0, 0, 0);
    }
    __syncthreads();
  }
  // ---- epilogue
#pragma unroll
  for (int r = 0; r < 4; ++r) {
    float inv = 1.f / l_r[r];
    int row = qb * 32 + wave * 16 + quad * 4 + r;
#pragma unroll
    for (int sub = 0; sub < 4; ++sub)
      attn[(size_t)row * 1024 + h * 64 + sub * 16 + l16] =
          __float2bfloat16(o[sub][r] * inv);
  }
}

// ---------------------------------------------------------------- router
__global__ void zero_counts_kernel(int* counts) {
  if (threadIdx.x < NE) counts[threadIdx.x] = 0;
}

__global__ void router_kernel(const float* __restrict__ h2, const float* __restrict__ rw,
                              int* counts, int* tok_list, int* topk_e, int* topk_pos,
                              float* topk_w) {
  int t = blockIdx.x;
  int lane = threadIdx.x;   // 64
  float p[NE] = {};
  for (int d = lane; d < D; d += 64) {
    float hv = h2[(size_t)t * D + d];
#pragma unroll
    for (int e = 0; e < NE; ++e) p[e] += hv * rw[d * NE + e];
  }
#pragma unroll
  for (int off = 32; off; off >>= 1)
#pragma unroll
    for (int e = 0; e < NE; ++e) p[e] += __shfl_xor(p[e], off);
  if (lane == 0) {
    float mx = p[0];
#pragma unroll
    for (int e = 1; e < NE; ++e) mx = fmaxf(mx, p[e]);
    float ex[NE];
#pragma unroll
    for (int e = 0; e < NE; ++e) ex[e] = __expf(p[e] - mx);
    int e0 = 0;
#pragma unroll
    for (int e = 1; e < NE; ++e) if (ex[e] > ex[e0]) e0 = e;
    int e1 = (e0 == 0) ? 1 : 0;
#pragma unroll
    for (int e = 0; e < NE; ++e) if (e != e0 && ex[e] > ex[e1]) e1 = e;
    float w0 = ex[e0] / (ex[e0] + ex[e1]);
    float w1 = ex[e1] / (ex[e0] + ex[e1]);
    int pos0 = atomicAdd(&counts[e0], 1);
    int pos1 = atomicAdd(&counts[e1], 1);
    tok_list[e0 * S + pos0] = t;
    tok_list[e1 * S + pos1] = t;
    topk_e[2 * t] = e0;  topk_e[2 * t + 1] = e1;
    topk_pos[2 * t] = pos0;  topk_pos[2 * t + 1] = pos1;
    topk_w[2 * t] = w0;  topk_w[2 * t + 1] = w1;
  }
}

__global__ void scan_kernel(const int* counts, int* offsets) {
  if (threadIdx.x == 0) {
    int acc = 0;
    for (int e = 0; e < NE; ++e) { offsets[e] = acc; acc += counts[e]; }
  }
}

// ---------------------------------------------------------------- final add
__global__ void final_kernel(const float* __restrict__ x, const float* __restrict__ sout,
                             const float* __restrict__ eo,
                             const int* __restrict__ topk_e, const int* __restrict__ topk_pos,
                             const float* __restrict__ topk_w, const int* __restrict__ offsets,
                             float* __restrict__ out) {
  int t = blockIdx.x;
  int tid = threadIdx.x;
  int e0 = topk_e[2 * t], e1 = topk_e[2 * t + 1];
  size_t r0 = (size_t)offsets[e0] + topk_pos[2 * t];
  size_t r1 = (size_t)offsets[e1] + topk_pos[2 * t + 1];
  float w0 = topk_w[2 * t], w1 = topk_w[2 * t + 1];
#pragma unroll
  for (int i = 0; i < 4; ++i) {
    int d = tid + i * 256;
    size_t idx = (size_t)t * D + d;
    out[idx] = x[idx] + sout[idx] + w0 * eo[r0 * D + d] + w1 * eo[r1 * D + d];
  }
}

extern "C" void kernel_launch(void* const* d_in, const int* in_sizes, int n_in,
                              void* d_out, int out_size, void* d_ws, size_t ws_size,
                              hipStream_t stream) {
  const float* hidden  = (const float*)d_in[0];
  const float* cosb    = (const float*)d_in[1];
  const float* sinb    = (const float*)d_in[2];
  const float* w_qkv   = (const float*)d_in[3];
  const float* w_o     = (const float*)d_in[4];
  const float* q_norm  = (const float*)d_in[5];
  const float* k_norm  = (const float*)d_in[6];
  const float* in_ln   = (const float*)d_in[7];
  const float* post_ln = (const float*)d_in[8];
  const float* router_w= (const float*)d_in[9];
  const float* w_gate  = (const float*)d_in[10];
  const float* w_up    = (const float*)d_in[11];
  const float* w_down  = (const float*)d_in[12];
  const float* ws_gate = (const float*)d_in[13];
  const float* ws_up   = (const float*)d_in[14];
  const float* ws_down = (const float*)d_in[15];
  float* out = (float*)d_out;
  float* ws = (float*)d_ws;

  typedef __hip_bfloat16 hbf;
  // weights (bf16)
  hbf* wqkvT = (hbf*)(ws);                      // 1.5M el
  hbf* woT   = (hbf*)(ws +  768 * 1024);        // 1M el
  hbf* wgT   = (hbf*)(ws + 1280 * 1024);        // 8M el
  hbf* wuT   = (hbf*)(ws + 5376 * 1024);        // 8M el
  hbf* wdT   = (hbf*)(ws + 9472 * 1024);        // 8M el
  hbf* wsgT  = (hbf*)(ws + 13568 * 1024);       // 1M el
  hbf* wsuT  = (hbf*)(ws + 14080 * 1024);       // 1M el
  hbf* wsdT  = (hbf*)(ws + 14592 * 1024);       // 1M el
  // activations
  hbf*   hb      = (hbf*)(ws + 15104 * 1024);   // [15104K,16128K)
  float* qkv     = ws + 16128 * 1024;           // [16128K,19200K)
  hbf*   qbB     = (hbf*)(ws + 19200 * 1024);   // 2M el  [19200K,20224K)
  hbf*   kbB     = (hbf*)(ws + 20224 * 1024);   // 512K el [20224K,20480K)
  hbf*   vbB     = (hbf*)(ws + 20480 * 1024);   // 512K el [20480K,20736K)
  hbf*   attnb16 = (hbf*)(ws + 20736 * 1024);   // 2M el  [20736K,21760K)
  float* x       = ws + 22784 * 1024;           // 2M fl
  float* h2      = ws + 24832 * 1024;           // 2M fl
  hbf*   h2b     = (hbf*)(ws + 26880 * 1024);   // 2M el
  hbf*   act     = (hbf*)(ws + 16128 * 1024);   // aliases qkv (dead after qkv_post)
  float* eo      = ws + 18176 * 1024;           // aliases q/k/v/attnb16 (dead after w_o)
  hbf*   sact    = (hbf*)(ws + 27904 * 1024);
  float* sout    = ws + 28928 * 1024;
  int* counts   = (int*)(ws + 30976 * 1024);
  int* offsets  = counts + NE;
  int* tok_list = offsets + NE;
  int* topk_e   = tok_list + NE * S;
  int* topk_pos = topk_e + 2 * S;
  float* topk_w = (float*)(topk_pos + 2 * S);

  dim3 b256(256);
  zero_counts_kernel<<<1, 64, 0, stream>>>(counts);
  transpose_cast_kernel<<<dim3(QKV_N/32, D/32, 1), b256, 0, stream>>>(w_qkv, wqkvT, D, QKV_N);
  transpose_cast_kernel<<<dim3(D/32, D/32, 1),     b256, 0, stream>>>(w_o, woT, D, D);
  transpose_cast_kernel<<<dim3(NI/32, D/32, NE),   b256, 0, stream>>>(w_gate, wgT, D, NI);
  transpose_cast_kernel<<<dim3(NI/32, D/32, NE),   b256, 0, stream>>>(w_up, wuT, D, NI);
  transpose_cast_kernel<<<dim3(D/32, NI/32, NE),   b256, 0, stream>>>(w_down, wdT, NI, D);
  transpose_cast_kernel<<<dim3(NI/32, D/32, 1),    b256, 0, stream>>>(ws_gate, wsgT, D, NI);
  transpose_cast_kernel<<<dim3(NI/32, D/32, 1),    b256, 0, stream>>>(ws_up, wsuT, D, NI);
  transpose_cast_kernel<<<dim3(D/32, NI/32, 1),    b256, 0, stream>>>(ws_down, wsdT, NI, D);
  // attention block
  rmsnorm_kernel<<<S, b256, 0, stream>>>(hidden, in_ln, nullptr, hb);
  mgemm_kernel<<<dim3(QKV_N/128, S/128, 1), b256, 0, stream>>>(hb, wqkvT, nullptr, qkv,
      S, QKV_N, D, nullptr, nullptr, nullptr, 0);
  qkv_post_kernel<<<dim3(S, 6), b256, 0, stream>>>(qkv, q_norm, k_norm, cosb, sinb, qbB, kbB, vbB);
  attn_kernel<<<dim3(S/32, NH), dim3(128), 0, stream>>>(qbB, kbB, vbB, attnb16);
  mgemm_kernel<<<dim3(D/128, S/128, 1), b256, 0, stream>>>(attnb16, woT, hidden, x,
      S, D, D, nullptr, nullptr, nullptr, 0);
  // MoE block
  rmsnorm_kernel<<<S, b256, 0, stream>>>(x, post_ln, h2, h2b);
  router_kernel<<<S, 64, 0, stream>>>(h2, router_w, counts, tok_list, topk_e, topk_pos, topk_w);
  scan_kernel<<<1, 64, 0, stream>>>(counts, offsets);
  mgemm_gu_kernel<<<dim3(NI/128, S/128, NE), b256, 0, stream>>>(h2b, wgT, wuT, act,
      S, NI, D, counts, offsets, tok_list);
  mgemm_kernel<<<dim3(D/128, S/128, NE), b256, 0, stream>>>(act, wdT, nullptr, eo,
      S, D, NI, counts, offsets, nullptr, 1);
  mgemm_gu_kernel<<<dim3(NI/128, S/128, 1), b256, 0, stream>>>(h2b, wsgT, wsuT, sact,
      S, NI, D, nullptr, nullptr, nullptr);
  mgemm_kernel<<<dim3(D/128, S/128, 1), b256, 0, stream>>>(sact, wsdT, nullptr, sout,
      S, D, NI, nullptr, nullptr, nullptr, 0);
  final_kernel<<<S, b256, 0, stream>>>(x, sout, eo, topk_e, topk_pos, topk_w, offsets, out);
}

// Round 8
// 562.803 us; speedup vs baseline: 3.6670x; 1.1938x over previous
//
#include <hip/hip_runtime.h>
#include <hip/hip_bf16.h>
#include <math.h>

#define S 2048
#define D 1024
#define NH 16
#define NKV 4
#define HD 64
#define QKV_N 1536          // (NH + 2*NKV) * HD
#define NE 8
#define NI 1024
#define EPS 1e-6f

typedef __bf16 bf16_t;
typedef __bf16 __attribute__((may_alias)) abf16;
typedef __attribute__((ext_vector_type(8))) __bf16 bf16x8;
typedef __attribute__((ext_vector_type(4))) float f32x4;
union I4B8 { int4 i; bf16x8 v; };

// ---------------------------------------------------------------- rmsnorm(D)
__global__ void rmsnorm_kernel(const float* __restrict__ in, const float* __restrict__ w,
                               float* __restrict__ out32, __hip_bfloat16* __restrict__ out16) {
  int t = blockIdx.x;
  int tid = threadIdx.x;
  const float* row = in + (size_t)t * D;
  float v[4];
  float ss = 0.f;
#pragma unroll
  for (int i = 0; i < 4; ++i) {
    v[i] = row[tid + i * 256];
    ss += v[i] * v[i];
  }
#pragma unroll
  for (int off = 32; off; off >>= 1) ss += __shfl_xor(ss, off);
  __shared__ float wsum[4];
  int wave = tid >> 6;
  if ((tid & 63) == 0) wsum[wave] = ss;
  __syncthreads();
  float tot = wsum[0] + wsum[1] + wsum[2] + wsum[3];
  float r = rsqrtf(tot / (float)D + EPS);
#pragma unroll
  for (int i = 0; i < 4; ++i) {
    int d = tid + i * 256;
    float val = v[i] * r * w[d];
    if (out32) out32[(size_t)t * D + d] = val;
    if (out16) out16[(size_t)t * D + d] = __float2bfloat16(val);
  }
}

// ------------------------------------------- weight transpose + bf16 cast
__global__ void transpose_cast_kernel(const float* __restrict__ W,
                                      __hip_bfloat16* __restrict__ WT, int Kd, int Nd) {
  __shared__ float tile[32][33];
  int e = blockIdx.z;
  const float* Wp = W + (size_t)e * Kd * Nd;
  __hip_bfloat16* WTp = WT + (size_t)e * Kd * Nd;
  int n0 = blockIdx.x * 32, k0 = blockIdx.y * 32;
  int tx = threadIdx.x & 31, ty = threadIdx.x >> 5;
#pragma unroll
  for (int i = 0; i < 4; ++i)
    tile[ty + i * 8][tx] = Wp[(size_t)(k0 + ty + i * 8) * Nd + n0 + tx];
  __syncthreads();
#pragma unroll
  for (int i = 0; i < 4; ++i)
    WTp[(size_t)(n0 + ty + i * 8) * Kd + k0 + tx] = __float2bfloat16(tile[tx][ty + i * 8]);
}

// ------------------------------------------- MFMA bf16 GEMM, 64x128 tile
// Fragment/epilogue geometry identical to R4-verified; A-tile is 64 rows.
// If counts!=null and blockIdx.z==NE: shared-expert override (As/BTs/Cs, identity rows).
__global__ __launch_bounds__(256) void mgemm_kernel(
    const __hip_bfloat16* __restrict__ A, const __hip_bfloat16* __restrict__ BT,
    const float* __restrict__ Cadd, float* __restrict__ C,
    int M, int N, int K,
    const int* __restrict__ counts, const int* __restrict__ offsets,
    const int* __restrict__ tok, int a_comp,
    const __hip_bfloat16* __restrict__ As2, const __hip_bfloat16* __restrict__ BTs2,
    float* __restrict__ Cs2) {
  __shared__ int AsI[64 * 20];    // 64 rows x 32 bf16, stride 20 ints
  __shared__ int BsI[128 * 20];
  __shared__ int rowmap[64];
  int e = blockIdx.z;
  bool sh = (counts != nullptr) && (e == NE);
  int cnt = sh ? M : (counts ? counts[e] : M);
  int bm = blockIdx.y * 64;
  if (bm >= cnt) return;
  int bn = blockIdx.x * 128;
  int obase = sh ? 0 : (offsets ? offsets[e] : 0);
  const bf16_t* Ab = sh ? (const bf16_t*)As2 : (const bf16_t*)A;
  const bf16_t* BTe = sh ? (const bf16_t*)BTs2 : ((const bf16_t*)BT + (size_t)e * N * K);
  float* Cp = sh ? Cs2 : C;
  const int* toke = (!sh && tok) ? tok + e * S : nullptr;
  int acompe = sh ? 0 : a_comp;
  int tid = threadIdx.x;
  if (tid < 64) {
    int gp = bm + tid;
    int cp = gp < cnt ? gp : cnt - 1;
    rowmap[tid] = toke ? toke[cp] : (acompe ? obase + cp : cp);
  }
  __syncthreads();
  int wave = tid >> 6, lane = tid & 63;
  int quad = lane >> 4, l16 = lane & 15;
  int wm = wave >> 1, wn = wave & 1;
  int pA = tid >> 2, qA = tid & 3;          // A staging: 64 rows x 4 int4
  int pB = tid >> 1, hf = tid & 1;          // B staging: 128 rows x 2x(2 int4)
  f32x4 acc[2][4];
#pragma unroll
  for (int i = 0; i < 2; ++i)
#pragma unroll
    for (int j = 0; j < 4; ++j) acc[i][j] = (f32x4){0.f, 0.f, 0.f, 0.f};
  for (int k0 = 0; k0 < K; k0 += 32) {
    int4 a0 = *(const int4*)(Ab + (size_t)rowmap[pA] * K + k0 + qA * 8);
    const int4* gb = (const int4*)(BTe + (size_t)(bn + pB) * K + k0 + hf * 16);
    int4 b0 = gb[0], b1 = gb[1];
    *(int4*)&AsI[pA * 20 + qA * 4] = a0;
    *(int4*)&BsI[pB * 20 + hf * 8] = b0;
    *(int4*)&BsI[pB * 20 + hf * 8 + 4] = b1;
    __syncthreads();
    I4B8 af[2], bfr[4];
#pragma unroll
    for (int s = 0; s < 2; ++s)
      af[s].i = *(const int4*)&AsI[(wm * 32 + s * 16 + l16) * 20 + quad * 4];
#pragma unroll
    for (int s = 0; s < 4; ++s)
      bfr[s].i = *(const int4*)&BsI[(wn * 64 + s * 16 + l16) * 20 + quad * 4];
#pragma unroll
    for (int i = 0; i < 2; ++i)
#pragma unroll
      for (int j = 0; j < 4; ++j)
        acc[i][j] = __builtin_amdgcn_mfma_f32_16x16x32_bf16(af[i].v, bfr[j].v, acc[i][j], 0, 0, 0);
    __syncthreads();
  }
#pragma unroll
  for (int i = 0; i < 2; ++i) {
#pragma unroll
    for (int r = 0; r < 4; ++r) {
      int trow = wm * 32 + i * 16 + quad * 4 + r;
      int gp = bm + trow;
      if (gp < cnt) {
        size_t rowb = (size_t)(obase + gp) * N;
#pragma unroll
        for (int j = 0; j < 4; ++j) {
          int col = bn + wn * 64 + j * 16 + l16;
          size_t idx = rowb + col;
          Cp[idx] = acc[i][j][r] + (Cadd ? Cadd[idx] : 0.f);
        }
      }
    }
  }
}

// ------------------------------------------- dual-B MFMA GEMM + silu, 64x128 tile
__global__ __launch_bounds__(256) void mgemm_gu_kernel(
    const __hip_bfloat16* __restrict__ A, const __hip_bfloat16* __restrict__ BTg,
    const __hip_bfloat16* __restrict__ BTu, __hip_bfloat16* __restrict__ act,
    int M, int N, int K,
    const int* __restrict__ counts, const int* __restrict__ offsets,
    const int* __restrict__ tok,
    const __hip_bfloat16* __restrict__ BTgs, const __hip_bfloat16* __restrict__ BTus,
    __hip_bfloat16* __restrict__ acts) {
  __shared__ int AsI[64 * 20];
  __shared__ int BgI[128 * 20];
  __shared__ int BuI[128 * 20];
  __shared__ int rowmap[64];
  int e = blockIdx.z;
  bool sh = (counts != nullptr) && (e == NE);
  int cnt = sh ? M : (counts ? counts[e] : M);
  int bm = blockIdx.y * 64;
  if (bm >= cnt) return;
  int bn = blockIdx.x * 128;
  int obase = sh ? 0 : (offsets ? offsets[e] : 0);
  const bf16_t* Ab = (const bf16_t*)A;
  const bf16_t* Bg = sh ? (const bf16_t*)BTgs : ((const bf16_t*)BTg + (size_t)e * N * K);
  const bf16_t* Bu = sh ? (const bf16_t*)BTus : ((const bf16_t*)BTu + (size_t)e * N * K);
  bf16_t* outp = sh ? (bf16_t*)acts : (bf16_t*)act;
  const int* toke = (!sh && tok) ? tok + e * S : nullptr;
  int tid = threadIdx.x;
  if (tid < 64) {
    int gp = bm + tid;
    int cp = gp < cnt ? gp : cnt - 1;
    rowmap[tid] = toke ? toke[cp] : cp;
  }
  __syncthreads();
  int wave = tid >> 6, lane = tid & 63;
  int quad = lane >> 4, l16 = lane & 15;
  int wm = wave >> 1, wn = wave & 1;
  int pA = tid >> 2, qA = tid & 3;
  int pB = tid >> 1, hf = tid & 1;
  f32x4 accg[2][4], accu[2][4];
#pragma unroll
  for (int i = 0; i < 2; ++i)
#pragma unroll
    for (int j = 0; j < 4; ++j) {
      accg[i][j] = (f32x4){0.f, 0.f, 0.f, 0.f};
      accu[i][j] = (f32x4){0.f, 0.f, 0.f, 0.f};
    }
  for (int k0 = 0; k0 < K; k0 += 32) {
    int4 a0 = *(const int4*)(Ab + (size_t)rowmap[pA] * K + k0 + qA * 8);
    const int4* gg = (const int4*)(Bg + (size_t)(bn + pB) * K + k0 + hf * 16);
    int4 g0 = gg[0], g1 = gg[1];
    const int4* gu = (const int4*)(Bu + (size_t)(bn + pB) * K + k0 + hf * 16);
    int4 u0 = gu[0], u1 = gu[1];
    *(int4*)&AsI[pA * 20 + qA * 4] = a0;
    *(int4*)&BgI[pB * 20 + hf * 8] = g0;
    *(int4*)&BgI[pB * 20 + hf * 8 + 4] = g1;
    *(int4*)&BuI[pB * 20 + hf * 8] = u0;
    *(int4*)&BuI[pB * 20 + hf * 8 + 4] = u1;
    __syncthreads();
    I4B8 af[2], bg[4], bu[4];
#pragma unroll
    for (int s = 0; s < 2; ++s)
      af[s].i = *(const int4*)&AsI[(wm * 32 + s * 16 + l16) * 20 + quad * 4];
#pragma unroll
    for (int s = 0; s < 4; ++s) {
      bg[s].i = *(const int4*)&BgI[(wn * 64 + s * 16 + l16) * 20 + quad * 4];
      bu[s].i = *(const int4*)&BuI[(wn * 64 + s * 16 + l16) * 20 + quad * 4];
    }
#pragma unroll
    for (int i = 0; i < 2; ++i)
#pragma unroll
      for (int j = 0; j < 4; ++j) {
        accg[i][j] = __builtin_amdgcn_mfma_f32_16x16x32_bf16(af[i].v, bg[j].v, accg[i][j], 0, 0, 0);
        accu[i][j] = __builtin_amdgcn_mfma_f32_16x16x32_bf16(af[i].v, bu[j].v, accu[i][j], 0, 0, 0);
      }
    __syncthreads();
  }
#pragma unroll
  for (int i = 0; i < 2; ++i) {
#pragma unroll
    for (int r = 0; r < 4; ++r) {
      int trow = wm * 32 + i * 16 + quad * 4 + r;
      int gp = bm + trow;
      if (gp < cnt) {
        size_t rowb = (size_t)(obase + gp) * N;
#pragma unroll
        for (int j = 0; j < 4; ++j) {
          int col = bn + wn * 64 + j * 16 + l16;
          float g = accg[i][j][r], uu = accu[i][j][r];
          float sg = g / (1.f + __expf(-g));
          outp[rowb + col] = __float2bfloat16(sg * uu);
        }
      }
    }
  }
}

// --------------------------------------------- q/k head rmsnorm + RoPE + bf16 cast
__global__ void qkv_post_kernel(const float* __restrict__ qkv,
                                const float* __restrict__ qw, const float* __restrict__ kw,
                                const float* __restrict__ cosb, const float* __restrict__ sinb,
                                __hip_bfloat16* __restrict__ qout,
                                __hip_bfloat16* __restrict__ kout,
                                __hip_bfloat16* __restrict__ vout) {
  int t = blockIdx.x;
  int u = blockIdx.y * 4 + (threadIdx.x >> 6);
  int lane = threadIdx.x & 63;
  if (u >= NH + NKV) {                       // v: plain cast
    int h = u - NH - NKV;
    float xv = qkv[(size_t)t * QKV_N + (NH + NKV) * HD + h * HD + lane];
    vout[(size_t)t * (NKV * HD) + h * HD + lane] = __float2bfloat16(xv);
    return;
  }
  bool isq = (u < NH);
  int h = isq ? u : (u - NH);
  size_t src = (size_t)t * QKV_N + (isq ? (h * HD) : (NH * HD + h * HD)) + lane;
  float xv = qkv[src];
  float ss = xv * xv;
#pragma unroll
  for (int off = 32; off; off >>= 1) ss += __shfl_xor(ss, off);
  float r = rsqrtf(ss * (1.f / 64.f) + EPS);
  float xn = xv * r * (isq ? qw[lane] : kw[lane]);
  float other = __shfl_xor(xn, 32);
  float rot = (lane < 32) ? -other : other;
  float res = xn * cosb[t * 64 + lane] + rot * sinb[t * 64 + lane];
  if (isq) qout[(size_t)t * (NH * HD) + h * HD + lane] = __float2bfloat16(res * 0.125f);
  else     kout[(size_t)t * (NKV * HD) + h * HD + lane] = __float2bfloat16(res);
}

// --------------------------------------------- MFMA flash attention v2 (R7-verified)
__global__ __launch_bounds__(128) void attn_kernel(
    const __hip_bfloat16* __restrict__ qg, const __hip_bfloat16* __restrict__ kg,
    const __hip_bfloat16* __restrict__ vg, __hip_bfloat16* __restrict__ attn) {
  int qb = (int)(gridDim.x - 1) - (int)blockIdx.x;   // heavy blocks first
  int h = blockIdx.y;
  int kvh = h >> 2;
  int tid = threadIdx.x;
  int wave = tid >> 6, lane = tid & 63;
  int quad = lane >> 4, l16 = lane & 15;

  __shared__ __align__(16) int QsI[32 * 36];
  __shared__ __align__(16) int KsI[32 * 36];
  __shared__ __align__(16) int VsI[32 * 34];
  __shared__ __align__(16) int PsI[2][16 * 20];

#pragma unroll
  for (int i = 0; i < 2; ++i) {
    int idx = tid + i * 128;
    int p = idx >> 3, c = (idx & 7) * 4;
    *(int4*)&QsI[p * 36 + c] =
        *(const int4*)((const int*)qg + (size_t)(qb * 32 + p) * 512 + h * 32 + c);
  }
  __syncthreads();
  I4B8 qf[2];
#pragma unroll
  for (int ch = 0; ch < 2; ++ch)
    qf[ch].i = *(const int4*)&QsI[(wave * 16 + l16) * 36 + ch * 16 + quad * 4];

  float m_r[4], l_r[4];
  f32x4 o[4];
#pragma unroll
  for (int r = 0; r < 4; ++r) { m_r[r] = -1e30f; l_r[r] = 0.f; }
#pragma unroll
  for (int s4 = 0; s4 < 4; ++s4) o[s4] = (f32x4){0.f, 0.f, 0.f, 0.f};

  for (int kc = 0; kc <= qb; ++kc) {
#pragma unroll
    for (int i = 0; i < 2; ++i) {
      int idx = tid + i * 128;
      int p = idx >> 3, c = (idx & 7) * 4;
      *(int4*)&KsI[p * 36 + c] =
          *(const int4*)((const int*)kg + (size_t)(kc * 32 + p) * 128 + kvh * 32 + c);
    }
#pragma unroll
    for (int i = 0; i < 4; ++i) {
      int idx = tid + i * 128;
      int p = idx >> 4, c = (idx & 15) * 2;
      *(int2*)&VsI[p * 34 + c] =
          *(const int2*)((const int*)vg + (size_t)(kc * 32 + p) * 128 + kvh * 32 + c);
    }
    __syncthreads();
    f32x4 s[2];
    s[0] = (f32x4){0.f, 0.f, 0.f, 0.f};
    s[1] = (f32x4){0.f, 0.f, 0.f, 0.f};
#pragma unroll
    for (int sub = 0; sub < 2; ++sub) {
#pragma unroll
      for (int ch = 0; ch < 2; ++ch) {
        I4B8 bu;
        bu.i = *(const int4*)&KsI[(sub * 16 + l16) * 36 + ch * 16 + quad * 4];
        s[sub] = __builtin_amdgcn_mfma_f32_16x16x32_bf16(qf[ch].v, bu.v, s[sub], 0, 0, 0);
      }
    }
    abf16* pw = (abf16*)PsI[wave];
    float al[4];
#pragma unroll
    for (int r = 0; r < 4; ++r) {
      float v = fmaxf(s[0][r], s[1][r]);
#pragma unroll
      for (int off = 1; off < 16; off <<= 1) v = fmaxf(v, __shfl_xor(v, off));
      float mx = fmaxf(m_r[r], v);
      al[r] = __expf(m_r[r] - mx);
      m_r[r] = mx;
      float p0 = __expf(s[0][r] - mx);
      float p1 = __expf(s[1][r] - mx);
      float su = p0 + p1;
#pragma unroll
      for (int off = 1; off < 16; off <<= 1) su += __shfl_xor(su, off);
      l_r[r] = l_r[r] * al[r] + su;
      int prow = quad * 4 + r;
      pw[prow * 40 + l16] = (bf16_t)p0;
      pw[prow * 40 + 16 + l16] = (bf16_t)p1;
#pragma unroll
      for (int s4 = 0; s4 < 4; ++s4) o[s4][r] *= al[r];
    }
    __syncthreads();
    I4B8 pu;
    pu.i = *(const int4*)&PsI[wave][l16 * 20 + quad * 4];
    const abf16* vsb = (const abf16*)VsI;
#pragma unroll
    for (int sub = 0; sub < 4; ++sub) {
      union { bf16_t e[8]; bf16x8 v; } vu;
#pragma unroll
      for (int j = 0; j < 8; ++j)
        vu.e[j] = vsb[(quad * 8 + j) * 68 + sub * 16 + l16];
      o[sub] = __builtin_amdgcn_mfma_f32_16x16x32_bf16(pu.v, vu.v, o[sub], 0, 0, 0);
    }
    __syncthreads();
  }
#pragma unroll
  for (int r = 0; r < 4; ++r) {
    float inv = 1.f / l_r[r];
    int row = qb * 32 + wave * 16 + quad * 4 + r;
#pragma unroll
    for (int sub = 0; sub < 4; ++sub)
      attn[(size_t)row * 1024 + h * 64 + sub * 16 + l16] =
          __float2bfloat16(o[sub][r] * inv);
  }
}

// ---------------------------------------------------------------- router
__global__ void zero_counts_kernel(int* counts) {
  if (threadIdx.x < NE) counts[threadIdx.x] = 0;
}

__global__ void router_kernel(const float* __restrict__ h2, const float* __restrict__ rw,
                              int* counts, int* tok_list, int* topk_e, int* topk_pos,
                              float* topk_w) {
  int t = blockIdx.x;
  int lane = threadIdx.x;   // 64
  float p[NE] = {};
  for (int d = lane; d < D; d += 64) {
    float hv = h2[(size_t)t * D + d];
#pragma unroll
    for (int e = 0; e < NE; ++e) p[e] += hv * rw[d * NE + e];
  }
#pragma unroll
  for (int off = 32; off; off >>= 1)
#pragma unroll
    for (int e = 0; e < NE; ++e) p[e] += __shfl_xor(p[e], off);
  if (lane == 0) {
    float mx = p[0];
#pragma unroll
    for (int e = 1; e < NE; ++e) mx = fmaxf(mx, p[e]);
    float ex[NE];
#pragma unroll
    for (int e = 0; e < NE; ++e) ex[e] = __expf(p[e] - mx);
    int e0 = 0;
#pragma unroll
    for (int e = 1; e < NE; ++e) if (ex[e] > ex[e0]) e0 = e;
    int e1 = (e0 == 0) ? 1 : 0;
#pragma unroll
    for (int e = 0; e < NE; ++e) if (e != e0 && ex[e] > ex[e1]) e1 = e;
    float w0 = ex[e0] / (ex[e0] + ex[e1]);
    float w1 = ex[e1] / (ex[e0] + ex[e1]);
    int pos0 = atomicAdd(&counts[e0], 1);
    int pos1 = atomicAdd(&counts[e1], 1);
    tok_list[e0 * S + pos0] = t;
    tok_list[e1 * S + pos1] = t;
    topk_e[2 * t] = e0;  topk_e[2 * t + 1] = e1;
    topk_pos[2 * t] = pos0;  topk_pos[2 * t + 1] = pos1;
    topk_w[2 * t] = w0;  topk_w[2 * t + 1] = w1;
  }
}

__global__ void scan_kernel(const int* counts, int* offsets) {
  if (threadIdx.x == 0) {
    int acc = 0;
    for (int e = 0; e < NE; ++e) { offsets[e] = acc; acc += counts[e]; }
  }
}

// ---------------------------------------------------------------- final add
__global__ void final_kernel(const float* __restrict__ x, const float* __restrict__ sout,
                             const float* __restrict__ eo,
                             const int* __restrict__ topk_e, const int* __restrict__ topk_pos,
                             const float* __restrict__ topk_w, const int* __restrict__ offsets,
                             float* __restrict__ out) {
  int t = blockIdx.x;
  int tid = threadIdx.x;
  int e0 = topk_e[2 * t], e1 = topk_e[2 * t + 1];
  size_t r0 = (size_t)offsets[e0] + topk_pos[2 * t];
  size_t r1 = (size_t)offsets[e1] + topk_pos[2 * t + 1];
  float w0 = topk_w[2 * t], w1 = topk_w[2 * t + 1];
#pragma unroll
  for (int i = 0; i < 4; ++i) {
    int d = tid + i * 256;
    size_t idx = (size_t)t * D + d;
    out[idx] = x[idx] + sout[idx] + w0 * eo[r0 * D + d] + w1 * eo[r1 * D + d];
  }
}

extern "C" void kernel_launch(void* const* d_in, const int* in_sizes, int n_in,
                              void* d_out, int out_size, void* d_ws, size_t ws_size,
                              hipStream_t stream) {
  const float* hidden  = (const float*)d_in[0];
  const float* cosb    = (const float*)d_in[1];
  const float* sinb    = (const float*)d_in[2];
  const float* w_qkv   = (const float*)d_in[3];
  const float* w_o     = (const float*)d_in[4];
  const float* q_norm  = (const float*)d_in[5];
  const float* k_norm  = (const float*)d_in[6];
  const float* in_ln   = (const float*)d_in[7];
  const float* post_ln = (const float*)d_in[8];
  const float* router_w= (const float*)d_in[9];
  const float* w_gate  = (const float*)d_in[10];
  const float* w_up    = (const float*)d_in[11];
  const float* w_down  = (const float*)d_in[12];
  const float* ws_gate = (const float*)d_in[13];
  const float* ws_up   = (const float*)d_in[14];
  const float* ws_down = (const float*)d_in[15];
  float* out = (float*)d_out;
  float* ws = (float*)d_ws;

  typedef __hip_bfloat16 hbf;
  // weights (bf16)
  hbf* wqkvT = (hbf*)(ws);                      // 1.5M el
  hbf* woT   = (hbf*)(ws +  768 * 1024);        // 1M el
  hbf* wgT   = (hbf*)(ws + 1280 * 1024);        // 8M el
  hbf* wuT   = (hbf*)(ws + 5376 * 1024);        // 8M el
  hbf* wdT   = (hbf*)(ws + 9472 * 1024);        // 8M el
  hbf* wsgT  = (hbf*)(ws + 13568 * 1024);       // 1M el
  hbf* wsuT  = (hbf*)(ws + 14080 * 1024);       // 1M el
  hbf* wsdT  = (hbf*)(ws + 14592 * 1024);       // 1M el
  // activations
  hbf*   hb      = (hbf*)(ws + 15104 * 1024);   // [15104K,16128K)
  float* qkv     = ws + 16128 * 1024;           // [16128K,19200K)
  hbf*   qbB     = (hbf*)(ws + 19200 * 1024);   // [19200K,20224K)
  hbf*   kbB     = (hbf*)(ws + 20224 * 1024);   // [20224K,20480K)
  hbf*   vbB     = (hbf*)(ws + 20480 * 1024);   // [20480K,20736K)
  hbf*   attnb16 = (hbf*)(ws + 20736 * 1024);   // [20736K,21760K)
  float* x       = ws + 22784 * 1024;           // 2M fl
  float* h2      = ws + 24832 * 1024;           // 2M fl
  hbf*   h2b     = (hbf*)(ws + 26880 * 1024);   // [26880K,27904K)
  hbf*   act     = (hbf*)(ws + 16128 * 1024);   // 4096x1024 bf16, aliases dead qkv
  float* eo      = ws + 18176 * 1024;           // 4096x1024 fp32, aliases dead q/k/v/attnb16
  hbf*   sact    = (hbf*)(ws + 27904 * 1024);   // 2048x1024 bf16
  float* sout    = ws + 28928 * 1024;           // 2048x1024 fp32
  int* counts   = (int*)(ws + 30976 * 1024);
  int* offsets  = counts + NE;
  int* tok_list = offsets + NE;
  int* topk_e   = tok_list + NE * S;
  int* topk_pos = topk_e + 2 * S;
  float* topk_w = (float*)(topk_pos + 2 * S);

  dim3 b256(256);
  zero_counts_kernel<<<1, 64, 0, stream>>>(counts);
  transpose_cast_kernel<<<dim3(QKV_N/32, D/32, 1), b256, 0, stream>>>(w_qkv, wqkvT, D, QKV_N);
  transpose_cast_kernel<<<dim3(D/32, D/32, 1),     b256, 0, stream>>>(w_o, woT, D, D);
  transpose_cast_kernel<<<dim3(NI/32, D/32, NE),   b256, 0, stream>>>(w_gate, wgT, D, NI);
  transpose_cast_kernel<<<dim3(NI/32, D/32, NE),   b256, 0, stream>>>(w_up, wuT, D, NI);
  transpose_cast_kernel<<<dim3(D/32, NI/32, NE),   b256, 0, stream>>>(w_down, wdT, NI, D);
  transpose_cast_kernel<<<dim3(NI/32, D/32, 1),    b256, 0, stream>>>(ws_gate, wsgT, D, NI);
  transpose_cast_kernel<<<dim3(NI/32, D/32, 1),    b256, 0, stream>>>(ws_up, wsuT, D, NI);
  transpose_cast_kernel<<<dim3(D/32, NI/32, 1),    b256, 0, stream>>>(ws_down, wsdT, NI, D);
  // attention block
  rmsnorm_kernel<<<S, b256, 0, stream>>>(hidden, in_ln, nullptr, hb);
  mgemm_kernel<<<dim3(QKV_N/128, S/64, 1), b256, 0, stream>>>(hb, wqkvT, nullptr, qkv,
      S, QKV_N, D, nullptr, nullptr, nullptr, 0, nullptr, nullptr, nullptr);
  qkv_post_kernel<<<dim3(S, 6), b256, 0, stream>>>(qkv, q_norm, k_norm, cosb, sinb, qbB, kbB, vbB);
  attn_kernel<<<dim3(S/32, NH), dim3(128), 0, stream>>>(qbB, kbB, vbB, attnb16);
  mgemm_kernel<<<dim3(D/128, S/64, 1), b256, 0, stream>>>(attnb16, woT, hidden, x,
      S, D, D, nullptr, nullptr, nullptr, 0, nullptr, nullptr, nullptr);
  // MoE block (shared expert merged as z == NE)
  rmsnorm_kernel<<<S, b256, 0, stream>>>(x, post_ln, h2, h2b);
  router_kernel<<<S, 64, 0, stream>>>(h2, router_w, counts, tok_list, topk_e, topk_pos, topk_w);
  scan_kernel<<<1, 64, 0, stream>>>(counts, offsets);
  mgemm_gu_kernel<<<dim3(NI/128, S/64, NE + 1), b256, 0, stream>>>(h2b, wgT, wuT, act,
      S, NI, D, counts, offsets, tok_list, wsgT, wsuT, sact);
  mgemm_kernel<<<dim3(D/128, S/64, NE + 1), b256, 0, stream>>>(act, wdT, nullptr, eo,
      S, D, NI, counts, offsets, nullptr, 1, sact, wsdT, sout);
  final_kernel<<<S, b256, 0, stream>>>(x, sout, eo, topk_e, topk_pos, topk_w, offsets, out);
}